// Round 5
// baseline (426.178 us; speedup 1.0000x reference)
//
#include <hip/hip_runtime.h>

// Problem constants (fixed by the reference)
#define NN 8192
#define EE 131072
#define MUL 128
#define AA 10
#define RB 8
#define DEF 264          // RB + 2*MUL
#define INV_SQRT3 0.5773502691896258f
#define INV_SQRT128 0.08838834764831845f
#define INV_SQRT10 0.31622776601683794f
#define INV_SQRT264 0.06154574548966636f

typedef __attribute__((ext_vector_type(8))) short short8;
typedef __attribute__((ext_vector_type(4))) float floatx4;

// ---------------------------------------------------------------------------
// Workspace layout (float offsets). ~182 MB total.
// ---------------------------------------------------------------------------
#define WS_XQ     ((size_t)0)                       // N*128 uint2 {us,uvx,uvy,uvz} bf16
#define WS_USB    (WS_XQ    + (size_t)NN*256)       // N*128 bf16
#define WS_UVB    (WS_USB   + (size_t)NN*64)        // 3*N*128 bf16 channel-major
#define WS_SRC    (WS_UVB   + (size_t)NN*192)       // N*128 bf16
#define WS_TGT    (WS_SRC   + (size_t)NN*64)        // N*128 bf16
#define WS_MSGSB  (WS_TGT   + (size_t)NN*64)        // N*256 bf16 (invden applied)
#define WS_MSGVB  (WS_MSGSB + (size_t)NN*128)       // 3*N*256 bf16 channel-major
#define WS_GATE   (WS_MSGVB + (size_t)NN*384)       // N*128 f32
#define WS_COUNTS (WS_GATE  + (size_t)NN*128)       // N ints
#define WS_OFFS   (WS_COUNTS+ (size_t)NN)           // N+4 ints
#define WS_CURSOR (WS_OFFS  + (size_t)(NN+4))       // N ints
#define WS_POS    (WS_CURSOR+ (size_t)NN)           // E ints
#define WS_META   (WS_POS   + (size_t)EE)           // E*8 f32
#define WS_TPW    (WS_META  + (size_t)EE*8)         // E*512 bf16, [slot][u][4] interleaved
#define WS_WB     (WS_TPW   + (size_t)EE*256)       // edge wfrags 152*512 bf16
#define WS_WP     (WS_WB    + (size_t)152*256)      // post wfrags 352*512 bf16

__device__ __forceinline__ float silu_f(float x) { return x / (1.f + __expf(-x)); }
__device__ __forceinline__ float sigm_f(float x) { return 1.f / (1.f + __expf(-x)); }

__device__ __forceinline__ unsigned short f2bf(float x) {
    union { float f; unsigned u; } uf; uf.f = x;
    unsigned r = uf.u + 0x7FFFu + ((uf.u >> 16) & 1u);   // RNE
    return (unsigned short)(r >> 16);
}
__device__ __forceinline__ float bf2f(unsigned short b) {
    union { unsigned u; float f; } uf; uf.u = ((unsigned)b) << 16;
    return uf.f;
}

// ---------------------------------------------------------------------------
// CSR build: count -> scan -> scatter   (receiver-sorted edge slots)
// ---------------------------------------------------------------------------
__global__ __launch_bounds__(256) void csr_count(
    const int* __restrict__ edge_index, int* __restrict__ counts)
{
    int e = blockIdx.x * 256 + threadIdx.x;
    atomicAdd(&counts[edge_index[EE + e]], 1);
}

__global__ __launch_bounds__(1024) void csr_scan(
    const int* __restrict__ counts, int* __restrict__ offs, int* __restrict__ cursor)
{
    __shared__ int sums[1024];
    const int t = threadIdx.x;
    int local[8];
    int s = 0;
#pragma unroll
    for (int k = 0; k < 8; ++k) { local[k] = s; s += counts[t * 8 + k]; }
    sums[t] = s;
    __syncthreads();
    for (int d = 1; d < 1024; d <<= 1) {
        int v = (t >= d) ? sums[t - d] : 0;
        __syncthreads();
        sums[t] += v;
        __syncthreads();
    }
    int base = (t > 0) ? sums[t - 1] : 0;
#pragma unroll
    for (int k = 0; k < 8; ++k) {
        offs[t * 8 + k] = base + local[k];
        cursor[t * 8 + k] = base + local[k];
    }
    if (t == 1023) offs[8192] = sums[1023];
}

__global__ __launch_bounds__(256) void csr_scatter(
    const int* __restrict__ edge_index, int* __restrict__ cursor, int* __restrict__ pos)
{
    int e = blockIdx.x * 256 + threadIdx.x;
    pos[e] = atomicAdd(&cursor[edge_index[EE + e]], 1);
}

// ---------------------------------------------------------------------------
// Edge weight pre-swizzle into MFMA B-fragment order (bf16, scales folded).
// ---------------------------------------------------------------------------
__global__ __launch_bounds__(256) void swizzle_weights(
    const float* __restrict__ Wr0, const float* __restrict__ Wd0,
    const float* __restrict__ Wr1, const float* __restrict__ Wr2,
    const float* __restrict__ Wr3, unsigned short* __restrict__ WBall)
{
    int fid = blockIdx.x * 256 + threadIdx.x;
    int lane = fid & 63;
    int frag = fid >> 6;
    int k0 = (lane >> 4) * 8;
    int n0 = lane & 15;
    unsigned short o[8];

    if (frag < 72) {
        int kt = frag >> 3, nt = frag & 7;
        int n = nt * 16 + n0;
#pragma unroll
        for (int j = 0; j < 8; ++j) {
            int k = kt * 32 + k0 + j;
            float v = 0.f;
            if (k < 264) v = ((n < 64) ? Wr0[k * 64 + n] : Wd0[k * 64 + (n - 64)]) * INV_SQRT264;
            o[j] = f2bf(v);
        }
    } else if (frag < 80) {
        int fl = frag - 72;
        int kt = fl >> 2, nt = fl & 3;
        int n = nt * 16 + n0;
#pragma unroll
        for (int j = 0; j < 8; ++j)
            o[j] = f2bf(Wr1[(kt * 32 + k0 + j) * 64 + n] * 0.125f);
    } else if (frag < 88) {
        int fl = frag - 80;
        int kt = fl >> 2, nt = fl & 3;
        int n = nt * 16 + n0;
#pragma unroll
        for (int j = 0; j < 8; ++j)
            o[j] = f2bf(Wr2[(kt * 32 + k0 + j) * 64 + n] * 0.125f);
    } else {
        int fl = frag - 88;
        int kt = fl >> 5, nt = fl & 31;
        int n = nt * 16 + n0;
        int q = n >> 6;
        float sc = (q < 2) ? 0.125f : 0.125f * INV_SQRT3;
#pragma unroll
        for (int j = 0; j < 8; ++j)
            o[j] = f2bf(Wr3[(kt * 32 + k0 + j) * 512 + n] * sc);
    }
    uint4 pk;
    pk.x = (unsigned)o[0] | ((unsigned)o[1] << 16);
    pk.y = (unsigned)o[2] | ((unsigned)o[3] << 16);
    pk.z = (unsigned)o[4] | ((unsigned)o[5] << 16);
    pk.w = (unsigned)o[6] | ((unsigned)o[7] << 16);
    *(uint4*)(WBall + (size_t)fid * 8) = pk;
}

// ---------------------------------------------------------------------------
// Post weight pre-swizzle (unchanged from round 4).
// ---------------------------------------------------------------------------
__global__ __launch_bounds__(256) void swizzle_post(
    const float* __restrict__ W1s, const float* __restrict__ W1v,
    const float* __restrict__ Wrs, const float* __restrict__ Wrv,
    const float* __restrict__ W2s, const float* __restrict__ W2v,
    unsigned short* __restrict__ WPall)
{
    int fid = blockIdx.x * 256 + threadIdx.x;
    int lane = fid & 63;
    int frag = fid >> 6;
    int k0 = (lane >> 4) * 8;
    int n0 = lane & 15;
    unsigned short o[8];

    if (frag < 192) {
        int kt = frag >> 4, nt = frag & 15;
        int n = nt * 16 + n0;
#pragma unroll
        for (int j = 0; j < 8; ++j) {
            int k = kt * 32 + k0 + j;
            float v = (k < 256) ? W1s[k * 256 + n] * 0.0625f
                                : Wrs[(k - 256) * 256 + n] * INV_SQRT128;
            o[j] = f2bf(v);
        }
    } else if (frag < 288) {
        int fl = frag - 192;
        int kt = fl >> 3, nt = fl & 7;
        int n = nt * 16 + n0;
#pragma unroll
        for (int j = 0; j < 8; ++j) {
            int k = kt * 32 + k0 + j;
            float v = (k < 256) ? W1v[k * 128 + n] * 0.0625f
                                : Wrv[(k - 256) * 128 + n] * INV_SQRT128;
            o[j] = f2bf(v);
        }
    } else if (frag < 320) {
        int fl = frag - 288;
        int kt = fl >> 3, nt = fl & 7;
        int n = nt * 16 + n0;
#pragma unroll
        for (int j = 0; j < 8; ++j)
            o[j] = f2bf(W2s[(kt * 32 + k0 + j) * 128 + n] * INV_SQRT128);
    } else {
        int fl = frag - 320;
        int kt = fl >> 3, nt = fl & 7;
        int n = nt * 16 + n0;
#pragma unroll
        for (int j = 0; j < 8; ++j)
            o[j] = f2bf(W2v[(kt * 32 + k0 + j) * 128 + n] * INV_SQRT128);
    }
    uint4 pk;
    pk.x = (unsigned)o[0] | ((unsigned)o[1] << 16);
    pk.y = (unsigned)o[2] | ((unsigned)o[3] << 16);
    pk.z = (unsigned)o[4] | ((unsigned)o[5] << 16);
    pk.w = (unsigned)o[6] | ((unsigned)o[7] << 16);
    *(uint4*)(WPall + (size_t)fid * 8) = pk;
}

// ---------------------------------------------------------------------------
// Kernel A: per-node precompute. sc (d_out), us/uv bf16, xq pack, srcE/tgtE.
// ---------------------------------------------------------------------------
#define NPB_A 8
__global__ __launch_bounds__(128) void node_pre(
    const float* __restrict__ node_attrs, const float* __restrict__ node_feats,
    const float* __restrict__ Wss, const float* __restrict__ Wsv,
    const float* __restrict__ Wus, const float* __restrict__ Wuv,
    const float* __restrict__ Wsrc, const float* __restrict__ Wtgt,
    float* __restrict__ sc_out,
    uint2* __restrict__ xq,
    unsigned short* __restrict__ us_b, unsigned short* __restrict__ uv_b,
    unsigned short* __restrict__ srcEb, unsigned short* __restrict__ tgtEb)
{
    __shared__ float s_l[NPB_A][128];
    __shared__ float v_l[NPB_A][384];
    __shared__ float a_l[NPB_A][AA];
    const int j = threadIdx.x;
    const int n0 = blockIdx.x * NPB_A;

    for (int idx = j; idx < NPB_A * 512; idx += 128) {
        int e = idx >> 9, k = idx & 511;
        float val = node_feats[(size_t)(n0 + e) * 512 + k];
        if (k < 128) s_l[e][k] = val; else v_l[e][k - 128] = val;
    }
    for (int idx = j; idx < NPB_A * AA; idx += 128) {
        int e = idx / AA, k = idx - e * AA;
        a_l[e][k] = node_attrs[(size_t)(n0 + e) * AA + k];
    }
    __syncthreads();

    float accS[NPB_A] = {0}, accU[NPB_A] = {0};
    float accSV[NPB_A][3] = {{0}}, accUV[NPB_A][3] = {{0}};
    float accSrc[NPB_A] = {0}, accTgt[NPB_A] = {0};

#pragma unroll 4
    for (int i = 0; i < 128; ++i) {
        float ws = Wss[i * 128 + j], wu = Wus[i * 128 + j];
#pragma unroll
        for (int e = 0; e < NPB_A; ++e) {
            float sv = s_l[e][i];
            accS[e] += sv * ws; accU[e] += sv * wu;
        }
    }
#pragma unroll 2
    for (int i = 0; i < 128; ++i) {
        float wsv = Wsv[i * 128 + j], wuv = Wuv[i * 128 + j];
#pragma unroll
        for (int e = 0; e < NPB_A; ++e) {
#pragma unroll
            for (int c = 0; c < 3; ++c) {
                float vv = v_l[e][i * 3 + c];
                accSV[e][c] += vv * wsv; accUV[e][c] += vv * wuv;
            }
        }
    }
#pragma unroll
    for (int i = 0; i < AA; ++i) {
        float w1 = Wsrc[i * 128 + j], w2 = Wtgt[i * 128 + j];
#pragma unroll
        for (int e = 0; e < NPB_A; ++e) {
            float av = a_l[e][i];
            accSrc[e] += av * w1; accTgt[e] += av * w2;
        }
    }

#pragma unroll
    for (int e = 0; e < NPB_A; ++e) {
        size_t n = n0 + e;
        sc_out[n * 512 + j] = accS[e] * INV_SQRT128;
#pragma unroll
        for (int c = 0; c < 3; ++c)
            sc_out[n * 512 + 128 + j * 3 + c] = accSV[e][c] * INV_SQRT128;
        float usv = accU[e] * INV_SQRT128;
        float uvx = accUV[e][0] * INV_SQRT128;
        float uvy = accUV[e][1] * INV_SQRT128;
        float uvz = accUV[e][2] * INV_SQRT128;
        us_b[n * 128 + j] = f2bf(usv);
        uv_b[((size_t)0 * NN + n) * 128 + j] = f2bf(uvx);
        uv_b[((size_t)1 * NN + n) * 128 + j] = f2bf(uvy);
        uv_b[((size_t)2 * NN + n) * 128 + j] = f2bf(uvz);
        uint2 p;
        p.x = (unsigned)f2bf(usv) | ((unsigned)f2bf(uvx) << 16);
        p.y = (unsigned)f2bf(uvy) | ((unsigned)f2bf(uvz) << 16);
        xq[n * 128 + j] = p;
        srcEb[n * 128 + j] = f2bf(accSrc[e] * INV_SQRT10);
        tgtEb[n * 128 + j] = f2bf(accTgt[e] * INV_SQRT10);
    }
}

// ---------------------------------------------------------------------------
// Kernel B: per-edge MLP on MFMA. 64 edges/block, 4 waves, 16-row slab each.
// h0/h1 live inside the (dead-after-L0, wave-private) region of efb:
//   h0 at cols [0,64), h1 at cols [80,144).  LDS ~39 KB -> 4 blocks/CU.
// tpw output layout: [slot][u][4] channel-interleaved (u in [0,128), g=w1..w4)
// ---------------------------------------------------------------------------
#define EBK 64
#define H1OFF 80
__global__ __launch_bounds__(256) void edge_mlp(
    const float* __restrict__ edge_attrs, const float* __restrict__ edge_feats,
    const int* __restrict__ edge_index,
    const unsigned short* __restrict__ srcEb, const unsigned short* __restrict__ tgtEb,
    const unsigned short* __restrict__ WB0, const unsigned short* __restrict__ WB1,
    const unsigned short* __restrict__ WB2, const unsigned short* __restrict__ WB3,
    const float* __restrict__ Wd1, const int* __restrict__ pos,
    unsigned short* __restrict__ tpwP, float* __restrict__ metaP)
{
    __shared__ __align__(16) unsigned short efb[EBK][296];
    __shared__ int snd_l[EBK], rcv_l[EBK], slot_l[EBK];
    __shared__ float y_l[EBK][4];

    const int t = threadIdx.x;
    const int l = t & 63;
    const int w = t >> 6;
    const int quad = l >> 4;
    const int lr = l & 15;
    const int e0 = blockIdx.x * EBK;

    if (t < EBK) {
        snd_l[t] = edge_index[e0 + t];
        rcv_l[t] = edge_index[EE + e0 + t];
        slot_l[t] = pos[e0 + t];
    }
    __syncthreads();

    if (t < EBK) {
        float4 ya = *(const float4*)(edge_attrs + (size_t)(e0 + t) * 4);
        y_l[t][0] = ya.x; y_l[t][1] = ya.y; y_l[t][2] = ya.z; y_l[t][3] = ya.w;
        float4 m;
        m.x = __int_as_float(snd_l[t]); m.y = ya.y; m.z = ya.z; m.w = ya.w;
        *(float4*)(metaP + (size_t)slot_l[t] * 8) = m;
        float4 f0 = *(const float4*)(edge_feats + (size_t)(e0 + t) * 8);
        float4 f1 = *(const float4*)(edge_feats + (size_t)(e0 + t) * 8 + 4);
        uint4 o;
        o.x = (unsigned)f2bf(f0.x) | ((unsigned)f2bf(f0.y) << 16);
        o.y = (unsigned)f2bf(f0.z) | ((unsigned)f2bf(f0.w) << 16);
        o.z = (unsigned)f2bf(f1.x) | ((unsigned)f2bf(f1.y) << 16);
        o.w = (unsigned)f2bf(f1.z) | ((unsigned)f2bf(f1.w) << 16);
        *(uint4*)&efb[t][0] = o;
    }
    for (int idx = t; idx < EBK * 16; idx += 256) {
        int e = idx >> 4, c = idx & 15;
        *(uint4*)&efb[e][8 + c * 8] =
            *(const uint4*)(srcEb + (size_t)snd_l[e] * 128 + c * 8);
        *(uint4*)&efb[e][136 + c * 8] =
            *(const uint4*)(tgtEb + (size_t)rcv_l[e] * 128 + c * 8);
    }
    for (int idx = t; idx < EBK * 3; idx += 256) {
        int e = idx / 3, c = idx - e * 3;
        uint4 z; z.x = 0; z.y = 0; z.z = 0; z.w = 0;
        *(uint4*)&efb[e][264 + c * 8] = z;
    }
    __syncthreads();

    const int rb = w * 16;
    int rowr[4], slotr[4];
    float y0r[4];
#pragma unroll
    for (int reg = 0; reg < 4; ++reg) {
        rowr[reg] = rb + quad * 4 + reg;
        slotr[reg] = slot_l[rowr[reg]];
        y0r[reg] = y_l[rowr[reg]][0];
    }
    float wd1v[4];
#pragma unroll
    for (int q2 = 0; q2 < 4; ++q2) wd1v[q2] = Wd1[q2 * 16 + lr] * 0.125f;

    // ---- layer0: ef[64x288] @ WB0[288x128] (cols 0-63 h0, 64-127 density d)
    floatx4 c0[8];
#pragma unroll
    for (int nt = 0; nt < 8; ++nt) c0[nt] = (floatx4){0.f, 0.f, 0.f, 0.f};
    const unsigned short* arow = &efb[rb + lr][quad * 8];
#pragma unroll
    for (int kt = 0; kt < 9; ++kt) {
        short8 af = *(const short8*)(arow + kt * 32);
        const short8* bp = (const short8*)WB0 + (size_t)(kt * 8) * 64 + l;
#pragma unroll
        for (int nt = 0; nt < 8; ++nt) {
            short8 bf = bp[nt * 64];
            c0[nt] = __builtin_amdgcn_mfma_f32_16x16x32_bf16(af, bf, c0[nt], 0, 0, 0);
        }
    }
    // h0 -> efb cols [0,64) of this wave's rows (dead after L0); d -> density
    float dp[4] = {0.f, 0.f, 0.f, 0.f};
#pragma unroll
    for (int nt = 0; nt < 4; ++nt) {
#pragma unroll
        for (int reg = 0; reg < 4; ++reg) {
            efb[rowr[reg]][nt * 16 + lr] = f2bf(silu_f(c0[nt][reg]));
            dp[reg] += silu_f(c0[nt + 4][reg]) * wd1v[nt];
        }
    }
#pragma unroll
    for (int m2 = 1; m2 < 16; m2 <<= 1) {
#pragma unroll
        for (int reg = 0; reg < 4; ++reg) dp[reg] += __shfl_xor(dp[reg], m2);
    }
    if (lr == 0) {
#pragma unroll
        for (int reg = 0; reg < 4; ++reg)
            metaP[(size_t)slotr[reg] * 8 + 4] = tanhf(dp[reg] * dp[reg]);
    }

    const unsigned short* hrow0 = &efb[rb + lr][quad * 8];
    const unsigned short* hrow1 = &efb[rb + lr][H1OFF + quad * 8];

    // ---- layer1: h0 @ WB1 -> h1 (cols [80,144))
    {
        floatx4 c1[4];
#pragma unroll
        for (int nt = 0; nt < 4; ++nt) c1[nt] = (floatx4){0.f, 0.f, 0.f, 0.f};
#pragma unroll
        for (int kt = 0; kt < 2; ++kt) {
            short8 af = *(const short8*)(hrow0 + kt * 32);
            const short8* bp = (const short8*)WB1 + (size_t)(kt * 4) * 64 + l;
#pragma unroll
            for (int nt = 0; nt < 4; ++nt)
                c1[nt] = __builtin_amdgcn_mfma_f32_16x16x32_bf16(af, bp[nt * 64], c1[nt], 0, 0, 0);
        }
#pragma unroll
        for (int nt = 0; nt < 4; ++nt)
#pragma unroll
            for (int reg = 0; reg < 4; ++reg)
                efb[rowr[reg]][H1OFF + nt * 16 + lr] = f2bf(silu_f(c1[nt][reg]));
    }

    // ---- layer2: h1 @ WB2 -> h2 (back into cols [0,64))
    {
        floatx4 c2[4];
#pragma unroll
        for (int nt = 0; nt < 4; ++nt) c2[nt] = (floatx4){0.f, 0.f, 0.f, 0.f};
#pragma unroll
        for (int kt = 0; kt < 2; ++kt) {
            short8 af = *(const short8*)(hrow1 + kt * 32);
            const short8* bp = (const short8*)WB2 + (size_t)(kt * 4) * 64 + l;
#pragma unroll
            for (int nt = 0; nt < 4; ++nt)
                c2[nt] = __builtin_amdgcn_mfma_f32_16x16x32_bf16(af, bp[nt * 64], c2[nt], 0, 0, 0);
        }
#pragma unroll
        for (int nt = 0; nt < 4; ++nt)
#pragma unroll
            for (int reg = 0; reg < 4; ++reg)
                efb[rowr[reg]][nt * 16 + lr] = f2bf(silu_f(c2[nt][reg]));
    }

    // ---- layer3: h2 @ WB3[64x512] -> tpw (scaled, bf16, interleaved [u][4])
#pragma unroll
    for (int g = 0; g < 4; ++g) {
        floatx4 c3[8];
#pragma unroll
        for (int j2 = 0; j2 < 8; ++j2) c3[j2] = (floatx4){0.f, 0.f, 0.f, 0.f};
#pragma unroll
        for (int kt = 0; kt < 2; ++kt) {
            short8 af = *(const short8*)(hrow0 + kt * 32);
            const short8* bp = (const short8*)WB3 + (size_t)(kt * 32 + g * 8) * 64 + l;
#pragma unroll
            for (int j2 = 0; j2 < 8; ++j2)
                c3[j2] = __builtin_amdgcn_mfma_f32_16x16x32_bf16(af, bp[j2 * 64], c3[j2], 0, 0, 0);
        }
        const bool usey0 = (g == 0) || (g == 2);   // w1 and w3 carry y0
#pragma unroll
        for (int j2 = 0; j2 < 8; ++j2) {
            int u = j2 * 16 + lr;
#pragma unroll
            for (int reg = 0; reg < 4; ++reg) {
                float val = c3[j2][reg] * (usey0 ? y0r[reg] : 1.f);
                tpwP[(size_t)slotr[reg] * 512 + u * 4 + g] = f2bf(val);
            }
        }
    }
}

// ---------------------------------------------------------------------------
// Kernel C: per-node gather (no atomics). block = 128 threads, 1 node.
// Per edge per thread: one uint2 tpw load (w1..w4) + one uint2 xq load.
// ---------------------------------------------------------------------------
__global__ __launch_bounds__(128) void node_gather(
    const unsigned short* __restrict__ tpwP, const float* __restrict__ metaP,
    const int* __restrict__ offs, const uint2* __restrict__ xq,
    const float* __restrict__ alpha_p, const float* __restrict__ beta_p,
    unsigned short* __restrict__ msgs_b, unsigned short* __restrict__ msgv_b)
{
    const int n = blockIdx.x;
    const int j = threadIdx.x;
    const int s0 = offs[n], s1 = offs[n + 1];
    const uint2* tpw2 = (const uint2*)tpwP;

    float as0 = 0.f, as1 = 0.f;
    float av0x = 0.f, av0y = 0.f, av0z = 0.f;
    float av1x = 0.f, av1y = 0.f, av1z = 0.f;
    float dsum = 0.f;

    for (int s = s0; s < s1; ++s) {
        const float4 m0 = *reinterpret_cast<const float4*>(&metaP[(size_t)s * 8]);
        const float dns = metaP[(size_t)s * 8 + 4];
        const int snd = __float_as_int(m0.x);
        const float y1x = m0.y, y1y = m0.z, y1z = m0.w;
        dsum += dns;

        uint2 wv = tpw2[(size_t)s * 128 + j];
        uint2 xv = xq[(size_t)snd * 128 + j];

        const float w1  = __uint_as_float(wv.x << 16);
        const float w2  = __uint_as_float(wv.x & 0xffff0000u);
        const float w3  = __uint_as_float(wv.y << 16);
        const float w4  = __uint_as_float(wv.y & 0xffff0000u);
        const float xs  = __uint_as_float(xv.x << 16);
        const float xvx = __uint_as_float(xv.x & 0xffff0000u);
        const float xvy = __uint_as_float(xv.y << 16);
        const float xvz = __uint_as_float(xv.y & 0xffff0000u);

        as0 += w1 * xs;
        as1 += w4 * (xvx * y1x + xvy * y1y + xvz * y1z);
        const float b2 = w2 * xs;
        av0x += b2 * y1x; av0y += b2 * y1y; av0z += b2 * y1z;
        av1x += w3 * xvx; av1y += w3 * xvy; av1z += w3 * xvz;
    }

    const float invden = 1.f / (dsum * (*beta_p) + (*alpha_p));

    msgs_b[(size_t)n * 256 + j]       = f2bf(as0 * invden);
    msgs_b[(size_t)n * 256 + 128 + j] = f2bf(as1 * invden);
    msgv_b[((size_t)0 * NN + n) * 256 + j]       = f2bf(av0x * invden);
    msgv_b[((size_t)0 * NN + n) * 256 + 128 + j] = f2bf(av1x * invden);
    msgv_b[((size_t)1 * NN + n) * 256 + j]       = f2bf(av0y * invden);
    msgv_b[((size_t)1 * NN + n) * 256 + 128 + j] = f2bf(av1y * invden);
    msgv_b[((size_t)2 * NN + n) * 256 + j]       = f2bf(av0z * invden);
    msgv_b[((size_t)2 * NN + n) * 256 + 128 + j] = f2bf(av1z * invden);
}

// ---------------------------------------------------------------------------
// Kernel D1: scalar epilogue on MFMA (unchanged from round 4).
// ---------------------------------------------------------------------------
#define DNP 32
__global__ __launch_bounds__(256) void post_s(
    const unsigned short* __restrict__ msgs_b, const unsigned short* __restrict__ us_b,
    const unsigned short* __restrict__ WPs, const unsigned short* __restrict__ W2ss,
    float* __restrict__ gate, float* __restrict__ out)
{
    __shared__ __align__(16) unsigned short At[DNP][392];
    __shared__ __align__(16) unsigned short osb[DNP][136];
    const int t = threadIdx.x;
    const int l = t & 63, w = t >> 6;
    const int quad = l >> 4, lr = l & 15;
    const int n0 = blockIdx.x * DNP;
    const int rt = w & 1, nh = w >> 1;

    for (int idx = t; idx < DNP * 48; idx += 256) {
        int r = idx / 48, q = idx - r * 48;
        uint4 v;
        if (q < 32) v = *(const uint4*)(msgs_b + (size_t)(n0 + r) * 256 + q * 8);
        else        v = *(const uint4*)(us_b   + (size_t)(n0 + r) * 128 + (q - 32) * 8);
        *(uint4*)&At[r][q * 8] = v;
    }
    __syncthreads();

    int rowr[4];
#pragma unroll
    for (int reg = 0; reg < 4; ++reg) rowr[reg] = rt * 16 + quad * 4 + reg;

    floatx4 c1[8];
#pragma unroll
    for (int nt = 0; nt < 8; ++nt) c1[nt] = (floatx4){0.f, 0.f, 0.f, 0.f};
    const unsigned short* arow = &At[rt * 16 + lr][quad * 8];
#pragma unroll
    for (int kt = 0; kt < 12; ++kt) {
        short8 af = *(const short8*)(arow + kt * 32);
        const short8* bp = (const short8*)WPs + (size_t)(kt * 16 + nh * 8) * 64 + l;
#pragma unroll
        for (int nt = 0; nt < 8; ++nt)
            c1[nt] = __builtin_amdgcn_mfma_f32_16x16x32_bf16(af, bp[nt * 64], c1[nt], 0, 0, 0);
    }
    if (nh == 0) {
#pragma unroll
        for (int nt = 0; nt < 8; ++nt)
#pragma unroll
            for (int reg = 0; reg < 4; ++reg)
                osb[rowr[reg]][nt * 16 + lr] = f2bf(silu_f(c1[nt][reg]));
    } else {
#pragma unroll
        for (int nt = 0; nt < 8; ++nt)
#pragma unroll
            for (int reg = 0; reg < 4; ++reg)
                gate[(size_t)(n0 + rowr[reg]) * 128 + nt * 16 + lr] = sigm_f(c1[nt][reg]);
    }
    __syncthreads();

    floatx4 c2[4];
#pragma unroll
    for (int nt = 0; nt < 4; ++nt) c2[nt] = (floatx4){0.f, 0.f, 0.f, 0.f};
    const unsigned short* arow2 = &osb[rt * 16 + lr][quad * 8];
#pragma unroll
    for (int kt = 0; kt < 4; ++kt) {
        short8 af = *(const short8*)(arow2 + kt * 32);
        const short8* bp = (const short8*)W2ss + (size_t)(kt * 8 + nh * 4) * 64 + l;
#pragma unroll
        for (int nt = 0; nt < 4; ++nt)
            c2[nt] = __builtin_amdgcn_mfma_f32_16x16x32_bf16(af, bp[nt * 64], c2[nt], 0, 0, 0);
    }
#pragma unroll
    for (int nt = 0; nt < 4; ++nt)
#pragma unroll
        for (int reg = 0; reg < 4; ++reg)
            out[(size_t)(n0 + rowr[reg]) * 512 + (nh * 64 + nt * 16 + lr) * 4] = c2[nt][reg];
}

// ---------------------------------------------------------------------------
// Kernel D2: vector epilogue on MFMA (unchanged from round 4).
// ---------------------------------------------------------------------------
__global__ __launch_bounds__(256) void post_v(
    const unsigned short* __restrict__ msgv_b, const unsigned short* __restrict__ uv_b,
    const unsigned short* __restrict__ WPv, const unsigned short* __restrict__ W2vs,
    const float* __restrict__ gate, float* __restrict__ out)
{
    __shared__ __align__(16) unsigned short At[DNP][392];
    __shared__ __align__(16) unsigned short ovb[DNP][136];
    const int t = threadIdx.x;
    const int l = t & 63, w = t >> 6;
    const int quad = l >> 4, lr = l & 15;
    const int c = blockIdx.x >> 8;
    const int n0 = (blockIdx.x & 255) * DNP;
    const int rt = w & 1, nh = w >> 1;

    for (int idx = t; idx < DNP * 48; idx += 256) {
        int r = idx / 48, q = idx - r * 48;
        uint4 v;
        if (q < 32) v = *(const uint4*)(msgv_b + ((size_t)c * NN + n0 + r) * 256 + q * 8);
        else        v = *(const uint4*)(uv_b   + ((size_t)c * NN + n0 + r) * 128 + (q - 32) * 8);
        *(uint4*)&At[r][q * 8] = v;
    }
    __syncthreads();

    int rowr[4];
#pragma unroll
    for (int reg = 0; reg < 4; ++reg) rowr[reg] = rt * 16 + quad * 4 + reg;

    floatx4 c1[4];
#pragma unroll
    for (int nt = 0; nt < 4; ++nt) c1[nt] = (floatx4){0.f, 0.f, 0.f, 0.f};
    const unsigned short* arow = &At[rt * 16 + lr][quad * 8];
#pragma unroll
    for (int kt = 0; kt < 12; ++kt) {
        short8 af = *(const short8*)(arow + kt * 32);
        const short8* bp = (const short8*)WPv + (size_t)(kt * 8 + nh * 4) * 64 + l;
#pragma unroll
        for (int nt = 0; nt < 4; ++nt)
            c1[nt] = __builtin_amdgcn_mfma_f32_16x16x32_bf16(af, bp[nt * 64], c1[nt], 0, 0, 0);
    }
#pragma unroll
    for (int nt = 0; nt < 4; ++nt)
#pragma unroll
        for (int reg = 0; reg < 4; ++reg) {
            int col = nh * 64 + nt * 16 + lr;
            float g = gate[(size_t)(n0 + rowr[reg]) * 128 + col];
            ovb[rowr[reg]][col] = f2bf(c1[nt][reg] * g);
        }
    __syncthreads();

    floatx4 c2[4];
#pragma unroll
    for (int nt = 0; nt < 4; ++nt) c2[nt] = (floatx4){0.f, 0.f, 0.f, 0.f};
    const unsigned short* arow2 = &ovb[rt * 16 + lr][quad * 8];
#pragma unroll
    for (int kt = 0; kt < 4; ++kt) {
        short8 af = *(const short8*)(arow2 + kt * 32);
        const short8* bp = (const short8*)W2vs + (size_t)(kt * 8 + nh * 4) * 64 + l;
#pragma unroll
        for (int nt = 0; nt < 4; ++nt)
            c2[nt] = __builtin_amdgcn_mfma_f32_16x16x32_bf16(af, bp[nt * 64], c2[nt], 0, 0, 0);
    }
#pragma unroll
    for (int nt = 0; nt < 4; ++nt)
#pragma unroll
        for (int reg = 0; reg < 4; ++reg)
            out[(size_t)(n0 + rowr[reg]) * 512 + (nh * 64 + nt * 16 + lr) * 4 + 1 + c]
                = c2[nt][reg];
}

// ---------------------------------------------------------------------------
extern "C" void kernel_launch(void* const* d_in, const int* in_sizes, int n_in,
                              void* d_out, int out_size, void* d_ws, size_t ws_size,
                              hipStream_t stream)
{
    const float* node_attrs = (const float*)d_in[0];
    const float* node_feats = (const float*)d_in[1];
    const float* edge_attrs = (const float*)d_in[2];
    const float* edge_feats = (const float*)d_in[3];
    const int*   edge_index = (const int*)d_in[4];
    const float* W_skip_s = (const float*)d_in[5];
    const float* W_skip_v = (const float*)d_in[6];
    const float* W_up_s   = (const float*)d_in[7];
    const float* W_up_v   = (const float*)d_in[8];
    const float* W_src    = (const float*)d_in[9];
    const float* W_tgt    = (const float*)d_in[10];
    const float* W_r0     = (const float*)d_in[11];
    const float* W_r1     = (const float*)d_in[12];
    const float* W_r2     = (const float*)d_in[13];
    const float* W_r3     = (const float*)d_in[14];
    const float* W_d0     = (const float*)d_in[15];
    const float* W_d1     = (const float*)d_in[16];
    const float* W1_s     = (const float*)d_in[17];
    const float* W1_v     = (const float*)d_in[18];
    const float* Wres_s   = (const float*)d_in[19];
    const float* Wres_v   = (const float*)d_in[20];
    const float* W2_s     = (const float*)d_in[21];
    const float* W2_v     = (const float*)d_in[22];
    const float* alpha_p  = (const float*)d_in[23];
    const float* beta_p   = (const float*)d_in[24];

    float* out = (float*)d_out;
    float* sc_out = out + (size_t)NN * 512;
    float* ws = (float*)d_ws;

    uint2* xq = (uint2*)(ws + WS_XQ);
    unsigned short* us_b  = (unsigned short*)(ws + WS_USB);
    unsigned short* uv_b  = (unsigned short*)(ws + WS_UVB);
    unsigned short* srcEb = (unsigned short*)(ws + WS_SRC);
    unsigned short* tgtEb = (unsigned short*)(ws + WS_TGT);
    unsigned short* msgs_b = (unsigned short*)(ws + WS_MSGSB);
    unsigned short* msgv_b = (unsigned short*)(ws + WS_MSGVB);
    float* gate  = ws + WS_GATE;
    int*   counts = (int*)(ws + WS_COUNTS);
    int*   offs   = (int*)(ws + WS_OFFS);
    int*   cursor = (int*)(ws + WS_CURSOR);
    int*   pos    = (int*)(ws + WS_POS);
    float* metaP  = ws + WS_META;
    unsigned short* tpwP = (unsigned short*)(ws + WS_TPW);
    unsigned short* WBall = (unsigned short*)(ws + WS_WB);
    unsigned short* WB0 = WBall;
    unsigned short* WB1 = WB0 + (size_t)72 * 512;
    unsigned short* WB2 = WB1 + (size_t)8 * 512;
    unsigned short* WB3 = WB2 + (size_t)8 * 512;
    unsigned short* WPall = (unsigned short*)(ws + WS_WP);
    unsigned short* WPs  = WPall;
    unsigned short* WPv  = WPs + (size_t)192 * 512;
    unsigned short* W2ss = WPv + (size_t)96 * 512;
    unsigned short* W2vs = W2ss + (size_t)32 * 512;

    hipMemsetAsync(counts, 0, (size_t)NN * sizeof(int), stream);

    csr_count<<<EE / 256, 256, 0, stream>>>(edge_index, counts);
    csr_scan<<<1, 1024, 0, stream>>>(counts, offs, cursor);
    csr_scatter<<<EE / 256, 256, 0, stream>>>(edge_index, cursor, pos);

    swizzle_weights<<<38, 256, 0, stream>>>(W_r0, W_d0, W_r1, W_r2, W_r3, WBall);
    swizzle_post<<<88, 256, 0, stream>>>(W1_s, W1_v, Wres_s, Wres_v, W2_s, W2_v, WPall);

    node_pre<<<NN / NPB_A, 128, 0, stream>>>(
        node_attrs, node_feats, W_skip_s, W_skip_v, W_up_s, W_up_v, W_src, W_tgt,
        sc_out, xq, us_b, uv_b, srcEb, tgtEb);

    edge_mlp<<<EE / EBK, 256, 0, stream>>>(
        edge_attrs, edge_feats, edge_index, srcEb, tgtEb,
        WB0, WB1, WB2, WB3, W_d1, pos, tpwP, metaP);

    node_gather<<<NN, 128, 0, stream>>>(
        tpwP, metaP, offs, xq, alpha_p, beta_p, msgs_b, msgv_b);

    post_s<<<NN / DNP, 256, 0, stream>>>(msgs_b, us_b, WPs, W2ss, gate, out);
    post_v<<<3 * NN / DNP, 256, 0, stream>>>(msgv_b, uv_b, WPv, W2vs, gate, out);
}

// Round 6
// 380.193 us; speedup vs baseline: 1.1209x; 1.1209x over previous
//
#include <hip/hip_runtime.h>

// Problem constants (fixed by the reference)
#define NN 8192
#define EE 131072
#define MUL 128
#define AA 10
#define RB 8
#define DEF 264          // RB + 2*MUL
#define INV_SQRT3 0.5773502691896258f
#define INV_SQRT128 0.08838834764831845f
#define INV_SQRT10 0.31622776601683794f
#define INV_SQRT264 0.06154574548966636f

typedef __attribute__((ext_vector_type(8))) short short8;
typedef __attribute__((ext_vector_type(4))) float floatx4;

// ---------------------------------------------------------------------------
// Workspace layout (float offsets). ~182 MB total.
// ---------------------------------------------------------------------------
#define WS_XQ     ((size_t)0)                       // N*128 uint2 {us,uvx,uvy,uvz} bf16
#define WS_USB    (WS_XQ    + (size_t)NN*256)       // N*128 bf16
#define WS_UVB    (WS_USB   + (size_t)NN*64)        // 3*N*128 bf16 channel-major
#define WS_SRC    (WS_UVB   + (size_t)NN*192)       // N*128 bf16
#define WS_TGT    (WS_SRC   + (size_t)NN*64)        // N*128 bf16
#define WS_MSGSB  (WS_TGT   + (size_t)NN*64)        // N*256 bf16 (invden applied)
#define WS_MSGVB  (WS_MSGSB + (size_t)NN*128)       // 3*N*256 bf16 channel-major
#define WS_GATE   (WS_MSGVB + (size_t)NN*384)       // N*128 f32
#define WS_COUNTS (WS_GATE  + (size_t)NN*128)       // N ints
#define WS_OFFS   (WS_COUNTS+ (size_t)NN)           // N+4 ints
#define WS_CURSOR (WS_OFFS  + (size_t)(NN+4))       // N ints
#define WS_POS    (WS_CURSOR+ (size_t)NN)           // E ints
#define WS_META   (WS_POS   + (size_t)EE)           // E*8 f32
#define WS_TPW    (WS_META  + (size_t)EE*8)         // E*512 bf16, [slot][u][4] interleaved
#define WS_WB     (WS_TPW   + (size_t)EE*256)       // edge wfrags 152*512 bf16
#define WS_WP     (WS_WB    + (size_t)152*256)      // post wfrags 352*512 bf16

__device__ __forceinline__ float silu_f(float x) { return x / (1.f + __expf(-x)); }
__device__ __forceinline__ float sigm_f(float x) { return 1.f / (1.f + __expf(-x)); }

__device__ __forceinline__ unsigned short f2bf(float x) {
    union { float f; unsigned u; } uf; uf.f = x;
    unsigned r = uf.u + 0x7FFFu + ((uf.u >> 16) & 1u);   // RNE
    return (unsigned short)(r >> 16);
}
__device__ __forceinline__ float bf2f(unsigned short b) {
    union { unsigned u; float f; } uf; uf.u = ((unsigned)b) << 16;
    return uf.f;
}

// ---------------------------------------------------------------------------
// CSR build: count -> scan -> scatter   (receiver-sorted edge slots)
// ---------------------------------------------------------------------------
__global__ __launch_bounds__(256) void csr_count(
    const int* __restrict__ edge_index, int* __restrict__ counts)
{
    int e = blockIdx.x * 256 + threadIdx.x;
    atomicAdd(&counts[edge_index[EE + e]], 1);
}

__global__ __launch_bounds__(1024) void csr_scan(
    const int* __restrict__ counts, int* __restrict__ offs, int* __restrict__ cursor)
{
    __shared__ int sums[1024];
    const int t = threadIdx.x;
    int local[8];
    int s = 0;
#pragma unroll
    for (int k = 0; k < 8; ++k) { local[k] = s; s += counts[t * 8 + k]; }
    sums[t] = s;
    __syncthreads();
    for (int d = 1; d < 1024; d <<= 1) {
        int v = (t >= d) ? sums[t - d] : 0;
        __syncthreads();
        sums[t] += v;
        __syncthreads();
    }
    int base = (t > 0) ? sums[t - 1] : 0;
#pragma unroll
    for (int k = 0; k < 8; ++k) {
        offs[t * 8 + k] = base + local[k];
        cursor[t * 8 + k] = base + local[k];
    }
    if (t == 1023) offs[8192] = sums[1023];
}

__global__ __launch_bounds__(256) void csr_scatter(
    const int* __restrict__ edge_index, int* __restrict__ cursor, int* __restrict__ pos)
{
    int e = blockIdx.x * 256 + threadIdx.x;
    pos[e] = atomicAdd(&cursor[edge_index[EE + e]], 1);
}

// ---------------------------------------------------------------------------
// Edge weight pre-swizzle into MFMA B-fragment order (bf16, scales folded).
// ---------------------------------------------------------------------------
__global__ __launch_bounds__(256) void swizzle_weights(
    const float* __restrict__ Wr0, const float* __restrict__ Wd0,
    const float* __restrict__ Wr1, const float* __restrict__ Wr2,
    const float* __restrict__ Wr3, unsigned short* __restrict__ WBall)
{
    int fid = blockIdx.x * 256 + threadIdx.x;
    int lane = fid & 63;
    int frag = fid >> 6;
    int k0 = (lane >> 4) * 8;
    int n0 = lane & 15;
    unsigned short o[8];

    if (frag < 72) {
        int kt = frag >> 3, nt = frag & 7;
        int n = nt * 16 + n0;
#pragma unroll
        for (int j = 0; j < 8; ++j) {
            int k = kt * 32 + k0 + j;
            float v = 0.f;
            if (k < 264) v = ((n < 64) ? Wr0[k * 64 + n] : Wd0[k * 64 + (n - 64)]) * INV_SQRT264;
            o[j] = f2bf(v);
        }
    } else if (frag < 80) {
        int fl = frag - 72;
        int kt = fl >> 2, nt = fl & 3;
        int n = nt * 16 + n0;
#pragma unroll
        for (int j = 0; j < 8; ++j)
            o[j] = f2bf(Wr1[(kt * 32 + k0 + j) * 64 + n] * 0.125f);
    } else if (frag < 88) {
        int fl = frag - 80;
        int kt = fl >> 2, nt = fl & 3;
        int n = nt * 16 + n0;
#pragma unroll
        for (int j = 0; j < 8; ++j)
            o[j] = f2bf(Wr2[(kt * 32 + k0 + j) * 64 + n] * 0.125f);
    } else {
        int fl = frag - 88;
        int kt = fl >> 5, nt = fl & 31;
        int n = nt * 16 + n0;
        int q = n >> 6;
        float sc = (q < 2) ? 0.125f : 0.125f * INV_SQRT3;
#pragma unroll
        for (int j = 0; j < 8; ++j)
            o[j] = f2bf(Wr3[(kt * 32 + k0 + j) * 512 + n] * sc);
    }
    uint4 pk;
    pk.x = (unsigned)o[0] | ((unsigned)o[1] << 16);
    pk.y = (unsigned)o[2] | ((unsigned)o[3] << 16);
    pk.z = (unsigned)o[4] | ((unsigned)o[5] << 16);
    pk.w = (unsigned)o[6] | ((unsigned)o[7] << 16);
    *(uint4*)(WBall + (size_t)fid * 8) = pk;
}

// ---------------------------------------------------------------------------
// Post weight pre-swizzle (unchanged).
// ---------------------------------------------------------------------------
__global__ __launch_bounds__(256) void swizzle_post(
    const float* __restrict__ W1s, const float* __restrict__ W1v,
    const float* __restrict__ Wrs, const float* __restrict__ Wrv,
    const float* __restrict__ W2s, const float* __restrict__ W2v,
    unsigned short* __restrict__ WPall)
{
    int fid = blockIdx.x * 256 + threadIdx.x;
    int lane = fid & 63;
    int frag = fid >> 6;
    int k0 = (lane >> 4) * 8;
    int n0 = lane & 15;
    unsigned short o[8];

    if (frag < 192) {
        int kt = frag >> 4, nt = frag & 15;
        int n = nt * 16 + n0;
#pragma unroll
        for (int j = 0; j < 8; ++j) {
            int k = kt * 32 + k0 + j;
            float v = (k < 256) ? W1s[k * 256 + n] * 0.0625f
                                : Wrs[(k - 256) * 256 + n] * INV_SQRT128;
            o[j] = f2bf(v);
        }
    } else if (frag < 288) {
        int fl = frag - 192;
        int kt = fl >> 3, nt = fl & 7;
        int n = nt * 16 + n0;
#pragma unroll
        for (int j = 0; j < 8; ++j) {
            int k = kt * 32 + k0 + j;
            float v = (k < 256) ? W1v[k * 128 + n] * 0.0625f
                                : Wrv[(k - 256) * 128 + n] * INV_SQRT128;
            o[j] = f2bf(v);
        }
    } else if (frag < 320) {
        int fl = frag - 288;
        int kt = fl >> 3, nt = fl & 7;
        int n = nt * 16 + n0;
#pragma unroll
        for (int j = 0; j < 8; ++j)
            o[j] = f2bf(W2s[(kt * 32 + k0 + j) * 128 + n] * INV_SQRT128);
    } else {
        int fl = frag - 320;
        int kt = fl >> 3, nt = fl & 7;
        int n = nt * 16 + n0;
#pragma unroll
        for (int j = 0; j < 8; ++j)
            o[j] = f2bf(W2v[(kt * 32 + k0 + j) * 128 + n] * INV_SQRT128);
    }
    uint4 pk;
    pk.x = (unsigned)o[0] | ((unsigned)o[1] << 16);
    pk.y = (unsigned)o[2] | ((unsigned)o[3] << 16);
    pk.z = (unsigned)o[4] | ((unsigned)o[5] << 16);
    pk.w = (unsigned)o[6] | ((unsigned)o[7] << 16);
    *(uint4*)(WPall + (size_t)fid * 8) = pk;
}

// ---------------------------------------------------------------------------
// Kernel A: per-node precompute. sc (d_out), us/uv bf16, xq pack, srcE/tgtE.
// ---------------------------------------------------------------------------
#define NPB_A 8
__global__ __launch_bounds__(128) void node_pre(
    const float* __restrict__ node_attrs, const float* __restrict__ node_feats,
    const float* __restrict__ Wss, const float* __restrict__ Wsv,
    const float* __restrict__ Wus, const float* __restrict__ Wuv,
    const float* __restrict__ Wsrc, const float* __restrict__ Wtgt,
    float* __restrict__ sc_out,
    uint2* __restrict__ xq,
    unsigned short* __restrict__ us_b, unsigned short* __restrict__ uv_b,
    unsigned short* __restrict__ srcEb, unsigned short* __restrict__ tgtEb)
{
    __shared__ float s_l[NPB_A][128];
    __shared__ float v_l[NPB_A][384];
    __shared__ float a_l[NPB_A][AA];
    const int j = threadIdx.x;
    const int n0 = blockIdx.x * NPB_A;

    for (int idx = j; idx < NPB_A * 512; idx += 128) {
        int e = idx >> 9, k = idx & 511;
        float val = node_feats[(size_t)(n0 + e) * 512 + k];
        if (k < 128) s_l[e][k] = val; else v_l[e][k - 128] = val;
    }
    for (int idx = j; idx < NPB_A * AA; idx += 128) {
        int e = idx / AA, k = idx - e * AA;
        a_l[e][k] = node_attrs[(size_t)(n0 + e) * AA + k];
    }
    __syncthreads();

    float accS[NPB_A] = {0}, accU[NPB_A] = {0};
    float accSV[NPB_A][3] = {{0}}, accUV[NPB_A][3] = {{0}};
    float accSrc[NPB_A] = {0}, accTgt[NPB_A] = {0};

#pragma unroll 4
    for (int i = 0; i < 128; ++i) {
        float ws = Wss[i * 128 + j], wu = Wus[i * 128 + j];
#pragma unroll
        for (int e = 0; e < NPB_A; ++e) {
            float sv = s_l[e][i];
            accS[e] += sv * ws; accU[e] += sv * wu;
        }
    }
#pragma unroll 2
    for (int i = 0; i < 128; ++i) {
        float wsv = Wsv[i * 128 + j], wuv = Wuv[i * 128 + j];
#pragma unroll
        for (int e = 0; e < NPB_A; ++e) {
#pragma unroll
            for (int c = 0; c < 3; ++c) {
                float vv = v_l[e][i * 3 + c];
                accSV[e][c] += vv * wsv; accUV[e][c] += vv * wuv;
            }
        }
    }
#pragma unroll
    for (int i = 0; i < AA; ++i) {
        float w1 = Wsrc[i * 128 + j], w2 = Wtgt[i * 128 + j];
#pragma unroll
        for (int e = 0; e < NPB_A; ++e) {
            float av = a_l[e][i];
            accSrc[e] += av * w1; accTgt[e] += av * w2;
        }
    }

#pragma unroll
    for (int e = 0; e < NPB_A; ++e) {
        size_t n = n0 + e;
        sc_out[n * 512 + j] = accS[e] * INV_SQRT128;
#pragma unroll
        for (int c = 0; c < 3; ++c)
            sc_out[n * 512 + 128 + j * 3 + c] = accSV[e][c] * INV_SQRT128;
        float usv = accU[e] * INV_SQRT128;
        float uvx = accUV[e][0] * INV_SQRT128;
        float uvy = accUV[e][1] * INV_SQRT128;
        float uvz = accUV[e][2] * INV_SQRT128;
        us_b[n * 128 + j] = f2bf(usv);
        uv_b[((size_t)0 * NN + n) * 128 + j] = f2bf(uvx);
        uv_b[((size_t)1 * NN + n) * 128 + j] = f2bf(uvy);
        uv_b[((size_t)2 * NN + n) * 128 + j] = f2bf(uvz);
        uint2 p;
        p.x = (unsigned)f2bf(usv) | ((unsigned)f2bf(uvx) << 16);
        p.y = (unsigned)f2bf(uvy) | ((unsigned)f2bf(uvz) << 16);
        xq[n * 128 + j] = p;
        srcEb[n * 128 + j] = f2bf(accSrc[e] * INV_SQRT10);
        tgtEb[n * 128 + j] = f2bf(accTgt[e] * INV_SQRT10);
    }
}

// ---------------------------------------------------------------------------
// Kernel B: per-edge MLP on MFMA. 64 edges/block, 4 waves, 16-row slab each.
// h0/h1 live inside the (dead-after-L0, wave-private) region of efb.
// Layer3 computes all 4 channels per u in registers, stores ONE uint2 per
// (u, edge) -> 32 dwordx2 stores/lane, each quad writes 128 contiguous B.
// ---------------------------------------------------------------------------
#define EBK 64
#define H1OFF 80
__global__ __launch_bounds__(256) void edge_mlp(
    const float* __restrict__ edge_attrs, const float* __restrict__ edge_feats,
    const int* __restrict__ edge_index,
    const unsigned short* __restrict__ srcEb, const unsigned short* __restrict__ tgtEb,
    const unsigned short* __restrict__ WB0, const unsigned short* __restrict__ WB1,
    const unsigned short* __restrict__ WB2, const unsigned short* __restrict__ WB3,
    const float* __restrict__ Wd1, const int* __restrict__ pos,
    unsigned short* __restrict__ tpwP, float* __restrict__ metaP)
{
    __shared__ __align__(16) unsigned short efb[EBK][296];
    __shared__ int snd_l[EBK], rcv_l[EBK], slot_l[EBK];
    __shared__ float y_l[EBK][4];

    const int t = threadIdx.x;
    const int l = t & 63;
    const int w = t >> 6;
    const int quad = l >> 4;
    const int lr = l & 15;
    const int e0 = blockIdx.x * EBK;

    if (t < EBK) {
        snd_l[t] = edge_index[e0 + t];
        rcv_l[t] = edge_index[EE + e0 + t];
        slot_l[t] = pos[e0 + t];
    }
    __syncthreads();

    if (t < EBK) {
        float4 ya = *(const float4*)(edge_attrs + (size_t)(e0 + t) * 4);
        y_l[t][0] = ya.x; y_l[t][1] = ya.y; y_l[t][2] = ya.z; y_l[t][3] = ya.w;
        float4 m;
        m.x = __int_as_float(snd_l[t]); m.y = ya.y; m.z = ya.z; m.w = ya.w;
        *(float4*)(metaP + (size_t)slot_l[t] * 8) = m;
        float4 f0 = *(const float4*)(edge_feats + (size_t)(e0 + t) * 8);
        float4 f1 = *(const float4*)(edge_feats + (size_t)(e0 + t) * 8 + 4);
        uint4 o;
        o.x = (unsigned)f2bf(f0.x) | ((unsigned)f2bf(f0.y) << 16);
        o.y = (unsigned)f2bf(f0.z) | ((unsigned)f2bf(f0.w) << 16);
        o.z = (unsigned)f2bf(f1.x) | ((unsigned)f2bf(f1.y) << 16);
        o.w = (unsigned)f2bf(f1.z) | ((unsigned)f2bf(f1.w) << 16);
        *(uint4*)&efb[t][0] = o;
    }
    for (int idx = t; idx < EBK * 16; idx += 256) {
        int e = idx >> 4, c = idx & 15;
        *(uint4*)&efb[e][8 + c * 8] =
            *(const uint4*)(srcEb + (size_t)snd_l[e] * 128 + c * 8);
        *(uint4*)&efb[e][136 + c * 8] =
            *(const uint4*)(tgtEb + (size_t)rcv_l[e] * 128 + c * 8);
    }
    for (int idx = t; idx < EBK * 3; idx += 256) {
        int e = idx / 3, c = idx - e * 3;
        uint4 z; z.x = 0; z.y = 0; z.z = 0; z.w = 0;
        *(uint4*)&efb[e][264 + c * 8] = z;
    }
    __syncthreads();

    const int rb = w * 16;
    int rowr[4], slotr[4];
    float y0r[4];
#pragma unroll
    for (int reg = 0; reg < 4; ++reg) {
        rowr[reg] = rb + quad * 4 + reg;
        slotr[reg] = slot_l[rowr[reg]];
        y0r[reg] = y_l[rowr[reg]][0];
    }
    float wd1v[4];
#pragma unroll
    for (int q2 = 0; q2 < 4; ++q2) wd1v[q2] = Wd1[q2 * 16 + lr] * 0.125f;

    // ---- layer0: ef[64x288] @ WB0[288x128] (cols 0-63 h0, 64-127 density d)
    floatx4 c0[8];
#pragma unroll
    for (int nt = 0; nt < 8; ++nt) c0[nt] = (floatx4){0.f, 0.f, 0.f, 0.f};
    const unsigned short* arow = &efb[rb + lr][quad * 8];
#pragma unroll
    for (int kt = 0; kt < 9; ++kt) {
        short8 af = *(const short8*)(arow + kt * 32);
        const short8* bp = (const short8*)WB0 + (size_t)(kt * 8) * 64 + l;
#pragma unroll
        for (int nt = 0; nt < 8; ++nt) {
            short8 bf = bp[nt * 64];
            c0[nt] = __builtin_amdgcn_mfma_f32_16x16x32_bf16(af, bf, c0[nt], 0, 0, 0);
        }
    }
    // h0 -> efb cols [0,64) of this wave's rows (dead after L0); d -> density
    float dp[4] = {0.f, 0.f, 0.f, 0.f};
#pragma unroll
    for (int nt = 0; nt < 4; ++nt) {
#pragma unroll
        for (int reg = 0; reg < 4; ++reg) {
            efb[rowr[reg]][nt * 16 + lr] = f2bf(silu_f(c0[nt][reg]));
            dp[reg] += silu_f(c0[nt + 4][reg]) * wd1v[nt];
        }
    }
#pragma unroll
    for (int m2 = 1; m2 < 16; m2 <<= 1) {
#pragma unroll
        for (int reg = 0; reg < 4; ++reg) dp[reg] += __shfl_xor(dp[reg], m2);
    }
    if (lr == 0) {
#pragma unroll
        for (int reg = 0; reg < 4; ++reg)
            metaP[(size_t)slotr[reg] * 8 + 4] = tanhf(dp[reg] * dp[reg]);
    }

    const unsigned short* hrow0 = &efb[rb + lr][quad * 8];
    const unsigned short* hrow1 = &efb[rb + lr][H1OFF + quad * 8];

    // ---- layer1: h0 @ WB1 -> h1 (cols [80,144))
    {
        floatx4 c1[4];
#pragma unroll
        for (int nt = 0; nt < 4; ++nt) c1[nt] = (floatx4){0.f, 0.f, 0.f, 0.f};
#pragma unroll
        for (int kt = 0; kt < 2; ++kt) {
            short8 af = *(const short8*)(hrow0 + kt * 32);
            const short8* bp = (const short8*)WB1 + (size_t)(kt * 4) * 64 + l;
#pragma unroll
            for (int nt = 0; nt < 4; ++nt)
                c1[nt] = __builtin_amdgcn_mfma_f32_16x16x32_bf16(af, bp[nt * 64], c1[nt], 0, 0, 0);
        }
#pragma unroll
        for (int nt = 0; nt < 4; ++nt)
#pragma unroll
            for (int reg = 0; reg < 4; ++reg)
                efb[rowr[reg]][H1OFF + nt * 16 + lr] = f2bf(silu_f(c1[nt][reg]));
    }

    // ---- layer2: h1 @ WB2 -> h2 (back into cols [0,64))
    {
        floatx4 c2[4];
#pragma unroll
        for (int nt = 0; nt < 4; ++nt) c2[nt] = (floatx4){0.f, 0.f, 0.f, 0.f};
#pragma unroll
        for (int kt = 0; kt < 2; ++kt) {
            short8 af = *(const short8*)(hrow1 + kt * 32);
            const short8* bp = (const short8*)WB2 + (size_t)(kt * 4) * 64 + l;
#pragma unroll
            for (int nt = 0; nt < 4; ++nt)
                c2[nt] = __builtin_amdgcn_mfma_f32_16x16x32_bf16(af, bp[nt * 64], c2[nt], 0, 0, 0);
        }
#pragma unroll
        for (int nt = 0; nt < 4; ++nt)
#pragma unroll
            for (int reg = 0; reg < 4; ++reg)
                efb[rowr[reg]][nt * 16 + lr] = f2bf(silu_f(c2[nt][reg]));
    }

    // ---- layer3: h2 @ WB3[64x512] -> tpw, 4 channels packed per uint2.
    // Channel nt-groups: g=0 -> w1 (xy0), g=1 -> w2, g=2 -> w3 (xy0), g=3 -> w4
    {
        short8 af0 = *(const short8*)(hrow0);
        short8 af1 = *(const short8*)(hrow0 + 32);
        uint2* tpw2 = (uint2*)tpwP;
#pragma unroll
        for (int j2 = 0; j2 < 8; ++j2) {
            floatx4 c3[4];
#pragma unroll
            for (int g = 0; g < 4; ++g) c3[g] = (floatx4){0.f, 0.f, 0.f, 0.f};
#pragma unroll
            for (int g = 0; g < 4; ++g) {
                const short8* b0 = (const short8*)WB3 + (size_t)(g * 8 + j2) * 64 + l;
                const short8* b1 = (const short8*)WB3 + (size_t)(32 + g * 8 + j2) * 64 + l;
                c3[g] = __builtin_amdgcn_mfma_f32_16x16x32_bf16(af0, *b0, c3[g], 0, 0, 0);
                c3[g] = __builtin_amdgcn_mfma_f32_16x16x32_bf16(af1, *b1, c3[g], 0, 0, 0);
            }
            const int u = j2 * 16 + lr;
#pragma unroll
            for (int reg = 0; reg < 4; ++reg) {
                float w1v = c3[0][reg] * y0r[reg];
                float w2v = c3[1][reg];
                float w3v = c3[2][reg] * y0r[reg];
                float w4v = c3[3][reg];
                uint2 p;
                p.x = (unsigned)f2bf(w1v) | ((unsigned)f2bf(w2v) << 16);
                p.y = (unsigned)f2bf(w3v) | ((unsigned)f2bf(w4v) << 16);
                tpw2[(size_t)slotr[reg] * 128 + u] = p;
            }
        }
    }
}

// ---------------------------------------------------------------------------
// Kernel C: per-node gather (no atomics). block = 128 threads, 1 node.
// Per edge per thread: one uint2 tpw load (w1..w4) + one uint2 xq load.
// ---------------------------------------------------------------------------
__global__ __launch_bounds__(128) void node_gather(
    const unsigned short* __restrict__ tpwP, const float* __restrict__ metaP,
    const int* __restrict__ offs, const uint2* __restrict__ xq,
    const float* __restrict__ alpha_p, const float* __restrict__ beta_p,
    unsigned short* __restrict__ msgs_b, unsigned short* __restrict__ msgv_b)
{
    const int n = blockIdx.x;
    const int j = threadIdx.x;
    const int s0 = offs[n], s1 = offs[n + 1];
    const uint2* tpw2 = (const uint2*)tpwP;

    float as0 = 0.f, as1 = 0.f;
    float av0x = 0.f, av0y = 0.f, av0z = 0.f;
    float av1x = 0.f, av1y = 0.f, av1z = 0.f;
    float dsum = 0.f;

    for (int s = s0; s < s1; ++s) {
        const float4 m0 = *reinterpret_cast<const float4*>(&metaP[(size_t)s * 8]);
        const float dns = metaP[(size_t)s * 8 + 4];
        const int snd = __float_as_int(m0.x);
        const float y1x = m0.y, y1y = m0.z, y1z = m0.w;
        dsum += dns;

        uint2 wv = tpw2[(size_t)s * 128 + j];
        uint2 xv = xq[(size_t)snd * 128 + j];

        const float w1  = __uint_as_float(wv.x << 16);
        const float w2  = __uint_as_float(wv.x & 0xffff0000u);
        const float w3  = __uint_as_float(wv.y << 16);
        const float w4  = __uint_as_float(wv.y & 0xffff0000u);
        const float xs  = __uint_as_float(xv.x << 16);
        const float xvx = __uint_as_float(xv.x & 0xffff0000u);
        const float xvy = __uint_as_float(xv.y << 16);
        const float xvz = __uint_as_float(xv.y & 0xffff0000u);

        as0 += w1 * xs;
        as1 += w4 * (xvx * y1x + xvy * y1y + xvz * y1z);
        const float b2 = w2 * xs;
        av0x += b2 * y1x; av0y += b2 * y1y; av0z += b2 * y1z;
        av1x += w3 * xvx; av1y += w3 * xvy; av1z += w3 * xvz;
    }

    const float invden = 1.f / (dsum * (*beta_p) + (*alpha_p));

    msgs_b[(size_t)n * 256 + j]       = f2bf(as0 * invden);
    msgs_b[(size_t)n * 256 + 128 + j] = f2bf(as1 * invden);
    msgv_b[((size_t)0 * NN + n) * 256 + j]       = f2bf(av0x * invden);
    msgv_b[((size_t)0 * NN + n) * 256 + 128 + j] = f2bf(av1x * invden);
    msgv_b[((size_t)1 * NN + n) * 256 + j]       = f2bf(av0y * invden);
    msgv_b[((size_t)1 * NN + n) * 256 + 128 + j] = f2bf(av1y * invden);
    msgv_b[((size_t)2 * NN + n) * 256 + j]       = f2bf(av0z * invden);
    msgv_b[((size_t)2 * NN + n) * 256 + 128 + j] = f2bf(av1z * invden);
}

// ---------------------------------------------------------------------------
// Kernel D1: scalar epilogue on MFMA (unchanged).
// ---------------------------------------------------------------------------
#define DNP 32
__global__ __launch_bounds__(256) void post_s(
    const unsigned short* __restrict__ msgs_b, const unsigned short* __restrict__ us_b,
    const unsigned short* __restrict__ WPs, const unsigned short* __restrict__ W2ss,
    float* __restrict__ gate, float* __restrict__ out)
{
    __shared__ __align__(16) unsigned short At[DNP][392];
    __shared__ __align__(16) unsigned short osb[DNP][136];
    const int t = threadIdx.x;
    const int l = t & 63, w = t >> 6;
    const int quad = l >> 4, lr = l & 15;
    const int n0 = blockIdx.x * DNP;
    const int rt = w & 1, nh = w >> 1;

    for (int idx = t; idx < DNP * 48; idx += 256) {
        int r = idx / 48, q = idx - r * 48;
        uint4 v;
        if (q < 32) v = *(const uint4*)(msgs_b + (size_t)(n0 + r) * 256 + q * 8);
        else        v = *(const uint4*)(us_b   + (size_t)(n0 + r) * 128 + (q - 32) * 8);
        *(uint4*)&At[r][q * 8] = v;
    }
    __syncthreads();

    int rowr[4];
#pragma unroll
    for (int reg = 0; reg < 4; ++reg) rowr[reg] = rt * 16 + quad * 4 + reg;

    floatx4 c1[8];
#pragma unroll
    for (int nt = 0; nt < 8; ++nt) c1[nt] = (floatx4){0.f, 0.f, 0.f, 0.f};
    const unsigned short* arow = &At[rt * 16 + lr][quad * 8];
#pragma unroll
    for (int kt = 0; kt < 12; ++kt) {
        short8 af = *(const short8*)(arow + kt * 32);
        const short8* bp = (const short8*)WPs + (size_t)(kt * 16 + nh * 8) * 64 + l;
#pragma unroll
        for (int nt = 0; nt < 8; ++nt)
            c1[nt] = __builtin_amdgcn_mfma_f32_16x16x32_bf16(af, bp[nt * 64], c1[nt], 0, 0, 0);
    }
    if (nh == 0) {
#pragma unroll
        for (int nt = 0; nt < 8; ++nt)
#pragma unroll
            for (int reg = 0; reg < 4; ++reg)
                osb[rowr[reg]][nt * 16 + lr] = f2bf(silu_f(c1[nt][reg]));
    } else {
#pragma unroll
        for (int nt = 0; nt < 8; ++nt)
#pragma unroll
            for (int reg = 0; reg < 4; ++reg)
                gate[(size_t)(n0 + rowr[reg]) * 128 + nt * 16 + lr] = sigm_f(c1[nt][reg]);
    }
    __syncthreads();

    floatx4 c2[4];
#pragma unroll
    for (int nt = 0; nt < 4; ++nt) c2[nt] = (floatx4){0.f, 0.f, 0.f, 0.f};
    const unsigned short* arow2 = &osb[rt * 16 + lr][quad * 8];
#pragma unroll
    for (int kt = 0; kt < 4; ++kt) {
        short8 af = *(const short8*)(arow2 + kt * 32);
        const short8* bp = (const short8*)W2ss + (size_t)(kt * 8 + nh * 4) * 64 + l;
#pragma unroll
        for (int nt = 0; nt < 4; ++nt)
            c2[nt] = __builtin_amdgcn_mfma_f32_16x16x32_bf16(af, bp[nt * 64], c2[nt], 0, 0, 0);
    }
#pragma unroll
    for (int nt = 0; nt < 4; ++nt)
#pragma unroll
        for (int reg = 0; reg < 4; ++reg)
            out[(size_t)(n0 + rowr[reg]) * 512 + (nh * 64 + nt * 16 + lr) * 4] = c2[nt][reg];
}

// ---------------------------------------------------------------------------
// Kernel D2: vector epilogue on MFMA (unchanged).
// ---------------------------------------------------------------------------
__global__ __launch_bounds__(256) void post_v(
    const unsigned short* __restrict__ msgv_b, const unsigned short* __restrict__ uv_b,
    const unsigned short* __restrict__ WPv, const unsigned short* __restrict__ W2vs,
    const float* __restrict__ gate, float* __restrict__ out)
{
    __shared__ __align__(16) unsigned short At[DNP][392];
    __shared__ __align__(16) unsigned short ovb[DNP][136];
    const int t = threadIdx.x;
    const int l = t & 63, w = t >> 6;
    const int quad = l >> 4, lr = l & 15;
    const int c = blockIdx.x >> 8;
    const int n0 = (blockIdx.x & 255) * DNP;
    const int rt = w & 1, nh = w >> 1;

    for (int idx = t; idx < DNP * 48; idx += 256) {
        int r = idx / 48, q = idx - r * 48;
        uint4 v;
        if (q < 32) v = *(const uint4*)(msgv_b + ((size_t)c * NN + n0 + r) * 256 + q * 8);
        else        v = *(const uint4*)(uv_b   + ((size_t)c * NN + n0 + r) * 128 + (q - 32) * 8);
        *(uint4*)&At[r][q * 8] = v;
    }
    __syncthreads();

    int rowr[4];
#pragma unroll
    for (int reg = 0; reg < 4; ++reg) rowr[reg] = rt * 16 + quad * 4 + reg;

    floatx4 c1[4];
#pragma unroll
    for (int nt = 0; nt < 4; ++nt) c1[nt] = (floatx4){0.f, 0.f, 0.f, 0.f};
    const unsigned short* arow = &At[rt * 16 + lr][quad * 8];
#pragma unroll
    for (int kt = 0; kt < 12; ++kt) {
        short8 af = *(const short8*)(arow + kt * 32);
        const short8* bp = (const short8*)WPv + (size_t)(kt * 8 + nh * 4) * 64 + l;
#pragma unroll
        for (int nt = 0; nt < 4; ++nt)
            c1[nt] = __builtin_amdgcn_mfma_f32_16x16x32_bf16(af, bp[nt * 64], c1[nt], 0, 0, 0);
    }
#pragma unroll
    for (int nt = 0; nt < 4; ++nt)
#pragma unroll
        for (int reg = 0; reg < 4; ++reg) {
            int col = nh * 64 + nt * 16 + lr;
            float g = gate[(size_t)(n0 + rowr[reg]) * 128 + col];
            ovb[rowr[reg]][col] = f2bf(c1[nt][reg] * g);
        }
    __syncthreads();

    floatx4 c2[4];
#pragma unroll
    for (int nt = 0; nt < 4; ++nt) c2[nt] = (floatx4){0.f, 0.f, 0.f, 0.f};
    const unsigned short* arow2 = &ovb[rt * 16 + lr][quad * 8];
#pragma unroll
    for (int kt = 0; kt < 4; ++kt) {
        short8 af = *(const short8*)(arow2 + kt * 32);
        const short8* bp = (const short8*)W2vs + (size_t)(kt * 8 + nh * 4) * 64 + l;
#pragma unroll
        for (int nt = 0; nt < 4; ++nt)
            c2[nt] = __builtin_amdgcn_mfma_f32_16x16x32_bf16(af, bp[nt * 64], c2[nt], 0, 0, 0);
    }
#pragma unroll
    for (int nt = 0; nt < 4; ++nt)
#pragma unroll
        for (int reg = 0; reg < 4; ++reg)
            out[(size_t)(n0 + rowr[reg]) * 512 + (nh * 64 + nt * 16 + lr) * 4 + 1 + c]
                = c2[nt][reg];
}

// ---------------------------------------------------------------------------
extern "C" void kernel_launch(void* const* d_in, const int* in_sizes, int n_in,
                              void* d_out, int out_size, void* d_ws, size_t ws_size,
                              hipStream_t stream)
{
    const float* node_attrs = (const float*)d_in[0];
    const float* node_feats = (const float*)d_in[1];
    const float* edge_attrs = (const float*)d_in[2];
    const float* edge_feats = (const float*)d_in[3];
    const int*   edge_index = (const int*)d_in[4];
    const float* W_skip_s = (const float*)d_in[5];
    const float* W_skip_v = (const float*)d_in[6];
    const float* W_up_s   = (const float*)d_in[7];
    const float* W_up_v   = (const float*)d_in[8];
    const float* W_src    = (const float*)d_in[9];
    const float* W_tgt    = (const float*)d_in[10];
    const float* W_r0     = (const float*)d_in[11];
    const float* W_r1     = (const float*)d_in[12];
    const float* W_r2     = (const float*)d_in[13];
    const float* W_r3     = (const float*)d_in[14];
    const float* W_d0     = (const float*)d_in[15];
    const float* W_d1     = (const float*)d_in[16];
    const float* W1_s     = (const float*)d_in[17];
    const float* W1_v     = (const float*)d_in[18];
    const float* Wres_s   = (const float*)d_in[19];
    const float* Wres_v   = (const float*)d_in[20];
    const float* W2_s     = (const float*)d_in[21];
    const float* W2_v     = (const float*)d_in[22];
    const float* alpha_p  = (const float*)d_in[23];
    const float* beta_p   = (const float*)d_in[24];

    float* out = (float*)d_out;
    float* sc_out = out + (size_t)NN * 512;
    float* ws = (float*)d_ws;

    uint2* xq = (uint2*)(ws + WS_XQ);
    unsigned short* us_b  = (unsigned short*)(ws + WS_USB);
    unsigned short* uv_b  = (unsigned short*)(ws + WS_UVB);
    unsigned short* srcEb = (unsigned short*)(ws + WS_SRC);
    unsigned short* tgtEb = (unsigned short*)(ws + WS_TGT);
    unsigned short* msgs_b = (unsigned short*)(ws + WS_MSGSB);
    unsigned short* msgv_b = (unsigned short*)(ws + WS_MSGVB);
    float* gate  = ws + WS_GATE;
    int*   counts = (int*)(ws + WS_COUNTS);
    int*   offs   = (int*)(ws + WS_OFFS);
    int*   cursor = (int*)(ws + WS_CURSOR);
    int*   pos    = (int*)(ws + WS_POS);
    float* metaP  = ws + WS_META;
    unsigned short* tpwP = (unsigned short*)(ws + WS_TPW);
    unsigned short* WBall = (unsigned short*)(ws + WS_WB);
    unsigned short* WB0 = WBall;
    unsigned short* WB1 = WB0 + (size_t)72 * 512;
    unsigned short* WB2 = WB1 + (size_t)8 * 512;
    unsigned short* WB3 = WB2 + (size_t)8 * 512;
    unsigned short* WPall = (unsigned short*)(ws + WS_WP);
    unsigned short* WPs  = WPall;
    unsigned short* WPv  = WPs + (size_t)192 * 512;
    unsigned short* W2ss = WPv + (size_t)96 * 512;
    unsigned short* W2vs = W2ss + (size_t)32 * 512;

    hipMemsetAsync(counts, 0, (size_t)NN * sizeof(int), stream);

    csr_count<<<EE / 256, 256, 0, stream>>>(edge_index, counts);
    csr_scan<<<1, 1024, 0, stream>>>(counts, offs, cursor);
    csr_scatter<<<EE / 256, 256, 0, stream>>>(edge_index, cursor, pos);

    swizzle_weights<<<38, 256, 0, stream>>>(W_r0, W_d0, W_r1, W_r2, W_r3, WBall);
    swizzle_post<<<88, 256, 0, stream>>>(W1_s, W1_v, Wres_s, Wres_v, W2_s, W2_v, WPall);

    node_pre<<<NN / NPB_A, 128, 0, stream>>>(
        node_attrs, node_feats, W_skip_s, W_skip_v, W_up_s, W_up_v, W_src, W_tgt,
        sc_out, xq, us_b, uv_b, srcEb, tgtEb);

    edge_mlp<<<EE / EBK, 256, 0, stream>>>(
        edge_attrs, edge_feats, edge_index, srcEb, tgtEb,
        WB0, WB1, WB2, WB3, W_d1, pos, tpwP, metaP);

    node_gather<<<NN, 128, 0, stream>>>(
        tpwP, metaP, offs, xq, alpha_p, beta_p, msgs_b, msgv_b);

    post_s<<<NN / DNP, 256, 0, stream>>>(msgs_b, us_b, WPs, W2ss, gate, out);
    post_v<<<3 * NN / DNP, 256, 0, stream>>>(msgv_b, uv_b, WPv, W2vs, gate, out);
}

// Round 7
// 320.264 us; speedup vs baseline: 1.3307x; 1.1871x over previous
//
#include <hip/hip_runtime.h>

// Problem constants (fixed by the reference)
#define NN 8192
#define EE 131072
#define MUL 128
#define AA 10
#define RB 8
#define DEF 264          // RB + 2*MUL
#define INV_SQRT3 0.5773502691896258f
#define INV_SQRT128 0.08838834764831845f
#define INV_SQRT10 0.31622776601683794f
#define INV_SQRT264 0.06154574548966636f

typedef __attribute__((ext_vector_type(8))) short short8;
typedef __attribute__((ext_vector_type(4))) float floatx4;

// ---------------------------------------------------------------------------
// Workspace layout (float offsets). ~182 MB total.
// ---------------------------------------------------------------------------
#define WS_XQ     ((size_t)0)                       // N*128 uint2 {us,uvx,uvy,uvz} bf16
#define WS_USB    (WS_XQ    + (size_t)NN*256)       // N*128 bf16
#define WS_UVB    (WS_USB   + (size_t)NN*64)        // 3*N*128 bf16 channel-major
#define WS_SRC    (WS_UVB   + (size_t)NN*192)       // N*128 bf16
#define WS_TGT    (WS_SRC   + (size_t)NN*64)        // N*128 bf16
#define WS_MSGSB  (WS_TGT   + (size_t)NN*64)        // N*256 bf16 (invden applied)
#define WS_MSGVB  (WS_MSGSB + (size_t)NN*128)       // 3*N*256 bf16 channel-major
#define WS_GATE   (WS_MSGVB + (size_t)NN*384)       // N*128 f32
#define WS_COUNTS (WS_GATE  + (size_t)NN*128)       // N ints
#define WS_OFFS   (WS_COUNTS+ (size_t)NN)           // N+4 ints
#define WS_CURSOR (WS_OFFS  + (size_t)(NN+4))       // N ints
#define WS_POS    (WS_CURSOR+ (size_t)NN)           // E ints
#define WS_META   (WS_POS   + (size_t)EE)           // E*8 f32
#define WS_TPW    (WS_META  + (size_t)EE*8)         // E*512 bf16, [slot][u][4] interleaved
#define WS_WB     (WS_TPW   + (size_t)EE*256)       // edge wfrags 152*512 bf16
#define WS_WP     (WS_WB    + (size_t)152*256)      // post wfrags 352*512 bf16
#define WS_WN     (WS_WP    + (size_t)352*256)      // node wfrags 144*512 bf16

__device__ __forceinline__ float silu_f(float x) { return x / (1.f + __expf(-x)); }
__device__ __forceinline__ float sigm_f(float x) { return 1.f / (1.f + __expf(-x)); }

__device__ __forceinline__ unsigned short f2bf(float x) {
    union { float f; unsigned u; } uf; uf.f = x;
    unsigned r = uf.u + 0x7FFFu + ((uf.u >> 16) & 1u);   // RNE
    return (unsigned short)(r >> 16);
}

// ---------------------------------------------------------------------------
// CSR build: count -> scan -> scatter   (receiver-sorted edge slots)
// ---------------------------------------------------------------------------
__global__ __launch_bounds__(256) void csr_count(
    const int* __restrict__ edge_index, int* __restrict__ counts)
{
    int e = blockIdx.x * 256 + threadIdx.x;
    atomicAdd(&counts[edge_index[EE + e]], 1);
}

__global__ __launch_bounds__(1024) void csr_scan(
    const int* __restrict__ counts, int* __restrict__ offs, int* __restrict__ cursor)
{
    __shared__ int sums[1024];
    const int t = threadIdx.x;
    int local[8];
    int s = 0;
#pragma unroll
    for (int k = 0; k < 8; ++k) { local[k] = s; s += counts[t * 8 + k]; }
    sums[t] = s;
    __syncthreads();
    for (int d = 1; d < 1024; d <<= 1) {
        int v = (t >= d) ? sums[t - d] : 0;
        __syncthreads();
        sums[t] += v;
        __syncthreads();
    }
    int base = (t > 0) ? sums[t - 1] : 0;
#pragma unroll
    for (int k = 0; k < 8; ++k) {
        offs[t * 8 + k] = base + local[k];
        cursor[t * 8 + k] = base + local[k];
    }
    if (t == 1023) offs[8192] = sums[1023];
}

__global__ __launch_bounds__(256) void csr_scatter(
    const int* __restrict__ edge_index, int* __restrict__ cursor, int* __restrict__ pos)
{
    int e = blockIdx.x * 256 + threadIdx.x;
    pos[e] = atomicAdd(&cursor[edge_index[EE + e]], 1);
}

// ---------------------------------------------------------------------------
// Edge weight pre-swizzle into MFMA B-fragment order (bf16, scales folded).
// ---------------------------------------------------------------------------
__global__ __launch_bounds__(256) void swizzle_weights(
    const float* __restrict__ Wr0, const float* __restrict__ Wd0,
    const float* __restrict__ Wr1, const float* __restrict__ Wr2,
    const float* __restrict__ Wr3, unsigned short* __restrict__ WBall)
{
    int fid = blockIdx.x * 256 + threadIdx.x;
    int lane = fid & 63;
    int frag = fid >> 6;
    int k0 = (lane >> 4) * 8;
    int n0 = lane & 15;
    unsigned short o[8];

    if (frag < 72) {
        int kt = frag >> 3, nt = frag & 7;
        int n = nt * 16 + n0;
#pragma unroll
        for (int j = 0; j < 8; ++j) {
            int k = kt * 32 + k0 + j;
            float v = 0.f;
            if (k < 264) v = ((n < 64) ? Wr0[k * 64 + n] : Wd0[k * 64 + (n - 64)]) * INV_SQRT264;
            o[j] = f2bf(v);
        }
    } else if (frag < 80) {
        int fl = frag - 72;
        int kt = fl >> 2, nt = fl & 3;
        int n = nt * 16 + n0;
#pragma unroll
        for (int j = 0; j < 8; ++j)
            o[j] = f2bf(Wr1[(kt * 32 + k0 + j) * 64 + n] * 0.125f);
    } else if (frag < 88) {
        int fl = frag - 80;
        int kt = fl >> 2, nt = fl & 3;
        int n = nt * 16 + n0;
#pragma unroll
        for (int j = 0; j < 8; ++j)
            o[j] = f2bf(Wr2[(kt * 32 + k0 + j) * 64 + n] * 0.125f);
    } else {
        int fl = frag - 88;
        int kt = fl >> 5, nt = fl & 31;
        int n = nt * 16 + n0;
        int q = n >> 6;
        float sc = (q < 2) ? 0.125f : 0.125f * INV_SQRT3;
#pragma unroll
        for (int j = 0; j < 8; ++j)
            o[j] = f2bf(Wr3[(kt * 32 + k0 + j) * 512 + n] * sc);
    }
    uint4 pk;
    pk.x = (unsigned)o[0] | ((unsigned)o[1] << 16);
    pk.y = (unsigned)o[2] | ((unsigned)o[3] << 16);
    pk.z = (unsigned)o[4] | ((unsigned)o[5] << 16);
    pk.w = (unsigned)o[6] | ((unsigned)o[7] << 16);
    *(uint4*)(WBall + (size_t)fid * 8) = pk;
}

// ---------------------------------------------------------------------------
// Post weight pre-swizzle (unchanged).
// ---------------------------------------------------------------------------
__global__ __launch_bounds__(256) void swizzle_post(
    const float* __restrict__ W1s, const float* __restrict__ W1v,
    const float* __restrict__ Wrs, const float* __restrict__ Wrv,
    const float* __restrict__ W2s, const float* __restrict__ W2v,
    unsigned short* __restrict__ WPall)
{
    int fid = blockIdx.x * 256 + threadIdx.x;
    int lane = fid & 63;
    int frag = fid >> 6;
    int k0 = (lane >> 4) * 8;
    int n0 = lane & 15;
    unsigned short o[8];

    if (frag < 192) {
        int kt = frag >> 4, nt = frag & 15;
        int n = nt * 16 + n0;
#pragma unroll
        for (int j = 0; j < 8; ++j) {
            int k = kt * 32 + k0 + j;
            float v = (k < 256) ? W1s[k * 256 + n] * 0.0625f
                                : Wrs[(k - 256) * 256 + n] * INV_SQRT128;
            o[j] = f2bf(v);
        }
    } else if (frag < 288) {
        int fl = frag - 192;
        int kt = fl >> 3, nt = fl & 7;
        int n = nt * 16 + n0;
#pragma unroll
        for (int j = 0; j < 8; ++j) {
            int k = kt * 32 + k0 + j;
            float v = (k < 256) ? W1v[k * 128 + n] * 0.0625f
                                : Wrv[(k - 256) * 128 + n] * INV_SQRT128;
            o[j] = f2bf(v);
        }
    } else if (frag < 320) {
        int fl = frag - 288;
        int kt = fl >> 3, nt = fl & 7;
        int n = nt * 16 + n0;
#pragma unroll
        for (int j = 0; j < 8; ++j)
            o[j] = f2bf(W2s[(kt * 32 + k0 + j) * 128 + n] * INV_SQRT128);
    } else {
        int fl = frag - 320;
        int kt = fl >> 3, nt = fl & 7;
        int n = nt * 16 + n0;
#pragma unroll
        for (int j = 0; j < 8; ++j)
            o[j] = f2bf(W2v[(kt * 32 + k0 + j) * 128 + n] * INV_SQRT128);
    }
    uint4 pk;
    pk.x = (unsigned)o[0] | ((unsigned)o[1] << 16);
    pk.y = (unsigned)o[2] | ((unsigned)o[3] << 16);
    pk.z = (unsigned)o[4] | ((unsigned)o[5] << 16);
    pk.w = (unsigned)o[6] | ((unsigned)o[7] << 16);
    *(uint4*)(WPall + (size_t)fid * 8) = pk;
}

// ---------------------------------------------------------------------------
// Node weight pre-swizzle (A-operand layout for the transposed node GEMM;
// the lane<->(k,m) map is identical to the B-frag swizzle).
// frags: [0,32) Wss  [32,64) Wus  [64,96) Wsv  [96,128) Wuv  (kt*8+mt, K=128)
//        [128,136) Wsrc  [136,144) Wtgt  (K=10 padded to 32)
// ---------------------------------------------------------------------------
__global__ __launch_bounds__(256) void swizzle_node(
    const float* __restrict__ Wss, const float* __restrict__ Wus,
    const float* __restrict__ Wsv, const float* __restrict__ Wuv,
    const float* __restrict__ Wsrc, const float* __restrict__ Wtgt,
    unsigned short* __restrict__ WN)
{
    int fid = blockIdx.x * 256 + threadIdx.x;   // 144*64 = 9216 = 36*256
    int lane = fid & 63;
    int frag = fid >> 6;
    int k0 = (lane >> 4) * 8;
    int m0 = lane & 15;
    unsigned short o[8];

    if (frag < 128) {
        int g = frag >> 5;
        int fl = frag & 31;
        int kt = fl >> 3, mt = fl & 7;
        const float* W = (g == 0) ? Wss : (g == 1) ? Wus : (g == 2) ? Wsv : Wuv;
        int m = mt * 16 + m0;
#pragma unroll
        for (int j = 0; j < 8; ++j)
            o[j] = f2bf(W[(kt * 32 + k0 + j) * 128 + m] * INV_SQRT128);
    } else {
        int g = (frag - 128) >> 3;
        int mt = frag & 7;
        const float* W = g ? Wtgt : Wsrc;
        int m = mt * 16 + m0;
#pragma unroll
        for (int j = 0; j < 8; ++j) {
            int k = k0 + j;
            o[j] = f2bf((k < AA) ? W[k * 128 + m] * INV_SQRT10 : 0.f);
        }
    }
    uint4 pk;
    pk.x = (unsigned)o[0] | ((unsigned)o[1] << 16);
    pk.y = (unsigned)o[2] | ((unsigned)o[3] << 16);
    pk.z = (unsigned)o[4] | ((unsigned)o[5] << 16);
    pk.w = (unsigned)o[6] | ((unsigned)o[7] << 16);
    *(uint4*)(WN + (size_t)fid * 8) = pk;
}

// ---------------------------------------------------------------------------
// Kernel A: per-node precompute on MFMA (transposed: C[j_out][node]).
// 16 nodes/block, 4 waves; wave handles mt in {2w, 2w+1} (j_out tiles of 16).
// Lane (quad,lr) holds outputs j0..j0+3 for node lr -> packed vector stores.
// ---------------------------------------------------------------------------
#define PNB 16
__global__ __launch_bounds__(256) void node_pre_mfma(
    const float* __restrict__ node_attrs, const float* __restrict__ node_feats,
    const unsigned short* __restrict__ WN,
    float* __restrict__ sc_out, uint2* __restrict__ xq,
    unsigned short* __restrict__ us_b, unsigned short* __restrict__ uv_b,
    unsigned short* __restrict__ srcEb, unsigned short* __restrict__ tgtEb)
{
    __shared__ __align__(16) unsigned short Xs[PNB][136];
    __shared__ __align__(16) unsigned short Xv[3][PNB][136];
    __shared__ __align__(16) unsigned short Xa[PNB][40];
    const int t = threadIdx.x;
    const int l = t & 63, w = t >> 6;
    const int quad = l >> 4, lr = l & 15;
    const int n0 = blockIdx.x * PNB;

    // ---- stage node_feats (f32 -> bf16): thread (r=t>>4, m=t&15)
    {
        const int r = t >> 4, m = t & 15;
        const float* src = node_feats + (size_t)(n0 + r) * 512;
        float4 s0 = *(const float4*)(src + 8 * m);
        float4 s1 = *(const float4*)(src + 8 * m + 4);
        uint4 sp;
        sp.x = (unsigned)f2bf(s0.x) | ((unsigned)f2bf(s0.y) << 16);
        sp.y = (unsigned)f2bf(s0.z) | ((unsigned)f2bf(s0.w) << 16);
        sp.z = (unsigned)f2bf(s1.x) | ((unsigned)f2bf(s1.y) << 16);
        sp.w = (unsigned)f2bf(s1.z) | ((unsigned)f2bf(s1.w) << 16);
        *(uint4*)&Xs[r][8 * m] = sp;

        float4 q[6];
#pragma unroll
        for (int jj = 0; jj < 6; ++jj)
            q[jj] = *(const float4*)(src + 128 + 24 * m + 4 * jj);
        const float* qf = &q[0].x;
        unsigned short vb[3][8];
#pragma unroll
        for (int u = 0; u < 8; ++u) {
#pragma unroll
            for (int c = 0; c < 3; ++c)
                vb[c][u] = f2bf(qf[u * 3 + c]);
        }
#pragma unroll
        for (int c = 0; c < 3; ++c) {
            uint4 vp;
            vp.x = (unsigned)vb[c][0] | ((unsigned)vb[c][1] << 16);
            vp.y = (unsigned)vb[c][2] | ((unsigned)vb[c][3] << 16);
            vp.z = (unsigned)vb[c][4] | ((unsigned)vb[c][5] << 16);
            vp.w = (unsigned)vb[c][6] | ((unsigned)vb[c][7] << 16);
            *(uint4*)&Xv[c][r][8 * m] = vp;
        }
    }
    // ---- stage attrs (padded K=32)
    for (int idx = t; idx < PNB * 32; idx += 256) {
        int r = idx >> 5, k = idx & 31;
        float v = (k < AA) ? node_attrs[(size_t)(n0 + r) * AA + k] : 0.f;
        Xa[r][k] = f2bf(v);
    }
    __syncthreads();

    const short8* WNf = (const short8*)WN;
    const int n = n0 + lr;

#pragma unroll
    for (int mi = 0; mi < 2; ++mi) {
        const int mt = w * 2 + mi;
        const int j0 = mt * 16 + quad * 4;

        // attr GEMM (K=32): srcE / tgtE
        floatx4 cSrc = (floatx4){0.f, 0.f, 0.f, 0.f};
        floatx4 cTgt = (floatx4){0.f, 0.f, 0.f, 0.f};
        {
            short8 ba = *(const short8*)&Xa[lr][quad * 8];
            cSrc = __builtin_amdgcn_mfma_f32_16x16x32_bf16(WNf[(size_t)(128 + mt) * 64 + l], ba, cSrc, 0, 0, 0);
            cTgt = __builtin_amdgcn_mfma_f32_16x16x32_bf16(WNf[(size_t)(136 + mt) * 64 + l], ba, cTgt, 0, 0, 0);
        }
        // s GEMMs (K=128): sc_s / us
        floatx4 cS = (floatx4){0.f, 0.f, 0.f, 0.f};
        floatx4 cU = (floatx4){0.f, 0.f, 0.f, 0.f};
#pragma unroll
        for (int kt = 0; kt < 4; ++kt) {
            short8 bs = *(const short8*)&Xs[lr][kt * 32 + quad * 8];
            cS = __builtin_amdgcn_mfma_f32_16x16x32_bf16(WNf[(size_t)(kt * 8 + mt) * 64 + l], bs, cS, 0, 0, 0);
            cU = __builtin_amdgcn_mfma_f32_16x16x32_bf16(WNf[(size_t)(32 + kt * 8 + mt) * 64 + l], bs, cU, 0, 0, 0);
        }
        // v GEMMs (K=128 x 3 channels): sc_v / uv
        floatx4 cSV[3], cUV[3];
#pragma unroll
        for (int c = 0; c < 3; ++c) {
            cSV[c] = (floatx4){0.f, 0.f, 0.f, 0.f};
            cUV[c] = (floatx4){0.f, 0.f, 0.f, 0.f};
#pragma unroll
            for (int kt = 0; kt < 4; ++kt) {
                short8 bv = *(const short8*)&Xv[c][lr][kt * 32 + quad * 8];
                cSV[c] = __builtin_amdgcn_mfma_f32_16x16x32_bf16(WNf[(size_t)(64 + kt * 8 + mt) * 64 + l], bv, cSV[c], 0, 0, 0);
                cUV[c] = __builtin_amdgcn_mfma_f32_16x16x32_bf16(WNf[(size_t)(96 + kt * 8 + mt) * 64 + l], bv, cUV[c], 0, 0, 0);
            }
        }

        // ---- epilogue: packed stores (node n, outputs j0..j0+3)
        {
            float4 o;
            o.x = cS[0]; o.y = cS[1]; o.z = cS[2]; o.w = cS[3];
            *(float4*)(sc_out + (size_t)n * 512 + j0) = o;
        }
        {
            float vv[12];
#pragma unroll
            for (int reg = 0; reg < 4; ++reg)
#pragma unroll
                for (int c = 0; c < 3; ++c) vv[reg * 3 + c] = cSV[c][reg];
            float* dst = sc_out + (size_t)n * 512 + 128 + j0 * 3;
#pragma unroll
            for (int qq = 0; qq < 3; ++qq) {
                float4 o;
                o.x = vv[qq * 4]; o.y = vv[qq * 4 + 1]; o.z = vv[qq * 4 + 2]; o.w = vv[qq * 4 + 3];
                *(float4*)(dst + qq * 4) = o;
            }
        }
        unsigned short ub[4], vxb[4], vyb[4], vzb[4];
#pragma unroll
        for (int reg = 0; reg < 4; ++reg) {
            ub[reg] = f2bf(cU[reg]);
            vxb[reg] = f2bf(cUV[0][reg]);
            vyb[reg] = f2bf(cUV[1][reg]);
            vzb[reg] = f2bf(cUV[2][reg]);
        }
        {
            uint2 p;
            p.x = (unsigned)ub[0] | ((unsigned)ub[1] << 16);
            p.y = (unsigned)ub[2] | ((unsigned)ub[3] << 16);
            *(uint2*)(us_b + (size_t)n * 128 + j0) = p;
        }
        {
            uint2 p;
            p.x = (unsigned)vxb[0] | ((unsigned)vxb[1] << 16);
            p.y = (unsigned)vxb[2] | ((unsigned)vxb[3] << 16);
            *(uint2*)(uv_b + ((size_t)0 * NN + n) * 128 + j0) = p;
            p.x = (unsigned)vyb[0] | ((unsigned)vyb[1] << 16);
            p.y = (unsigned)vyb[2] | ((unsigned)vyb[3] << 16);
            *(uint2*)(uv_b + ((size_t)1 * NN + n) * 128 + j0) = p;
            p.x = (unsigned)vzb[0] | ((unsigned)vzb[1] << 16);
            p.y = (unsigned)vzb[2] | ((unsigned)vzb[3] << 16);
            *(uint2*)(uv_b + ((size_t)2 * NN + n) * 128 + j0) = p;
        }
        {
            uint4 x0, x1;
            x0.x = (unsigned)ub[0] | ((unsigned)vxb[0] << 16);
            x0.y = (unsigned)vyb[0] | ((unsigned)vzb[0] << 16);
            x0.z = (unsigned)ub[1] | ((unsigned)vxb[1] << 16);
            x0.w = (unsigned)vyb[1] | ((unsigned)vzb[1] << 16);
            x1.x = (unsigned)ub[2] | ((unsigned)vxb[2] << 16);
            x1.y = (unsigned)vyb[2] | ((unsigned)vzb[2] << 16);
            x1.z = (unsigned)ub[3] | ((unsigned)vxb[3] << 16);
            x1.w = (unsigned)vyb[3] | ((unsigned)vzb[3] << 16);
            uint4* xp = (uint4*)(xq + (size_t)n * 128 + j0);
            xp[0] = x0; xp[1] = x1;
        }
        {
            uint2 p;
            p.x = (unsigned)f2bf(cSrc[0]) | ((unsigned)f2bf(cSrc[1]) << 16);
            p.y = (unsigned)f2bf(cSrc[2]) | ((unsigned)f2bf(cSrc[3]) << 16);
            *(uint2*)(srcEb + (size_t)n * 128 + j0) = p;
            p.x = (unsigned)f2bf(cTgt[0]) | ((unsigned)f2bf(cTgt[1]) << 16);
            p.y = (unsigned)f2bf(cTgt[2]) | ((unsigned)f2bf(cTgt[3]) << 16);
            *(uint2*)(tgtEb + (size_t)n * 128 + j0) = p;
        }
    }
}

// ---------------------------------------------------------------------------
// Kernel B: per-edge MLP on MFMA (unchanged from round 6).
// ---------------------------------------------------------------------------
#define EBK 64
#define H1OFF 80
__global__ __launch_bounds__(256) void edge_mlp(
    const float* __restrict__ edge_attrs, const float* __restrict__ edge_feats,
    const int* __restrict__ edge_index,
    const unsigned short* __restrict__ srcEb, const unsigned short* __restrict__ tgtEb,
    const unsigned short* __restrict__ WB0, const unsigned short* __restrict__ WB1,
    const unsigned short* __restrict__ WB2, const unsigned short* __restrict__ WB3,
    const float* __restrict__ Wd1, const int* __restrict__ pos,
    unsigned short* __restrict__ tpwP, float* __restrict__ metaP)
{
    __shared__ __align__(16) unsigned short efb[EBK][296];
    __shared__ int snd_l[EBK], rcv_l[EBK], slot_l[EBK];
    __shared__ float y_l[EBK][4];

    const int t = threadIdx.x;
    const int l = t & 63;
    const int w = t >> 6;
    const int quad = l >> 4;
    const int lr = l & 15;
    const int e0 = blockIdx.x * EBK;

    if (t < EBK) {
        snd_l[t] = edge_index[e0 + t];
        rcv_l[t] = edge_index[EE + e0 + t];
        slot_l[t] = pos[e0 + t];
    }
    __syncthreads();

    if (t < EBK) {
        float4 ya = *(const float4*)(edge_attrs + (size_t)(e0 + t) * 4);
        y_l[t][0] = ya.x; y_l[t][1] = ya.y; y_l[t][2] = ya.z; y_l[t][3] = ya.w;
        float4 m;
        m.x = __int_as_float(snd_l[t]); m.y = ya.y; m.z = ya.z; m.w = ya.w;
        *(float4*)(metaP + (size_t)slot_l[t] * 8) = m;
        float4 f0 = *(const float4*)(edge_feats + (size_t)(e0 + t) * 8);
        float4 f1 = *(const float4*)(edge_feats + (size_t)(e0 + t) * 8 + 4);
        uint4 o;
        o.x = (unsigned)f2bf(f0.x) | ((unsigned)f2bf(f0.y) << 16);
        o.y = (unsigned)f2bf(f0.z) | ((unsigned)f2bf(f0.w) << 16);
        o.z = (unsigned)f2bf(f1.x) | ((unsigned)f2bf(f1.y) << 16);
        o.w = (unsigned)f2bf(f1.z) | ((unsigned)f2bf(f1.w) << 16);
        *(uint4*)&efb[t][0] = o;
    }
    for (int idx = t; idx < EBK * 16; idx += 256) {
        int e = idx >> 4, c = idx & 15;
        *(uint4*)&efb[e][8 + c * 8] =
            *(const uint4*)(srcEb + (size_t)snd_l[e] * 128 + c * 8);
        *(uint4*)&efb[e][136 + c * 8] =
            *(const uint4*)(tgtEb + (size_t)rcv_l[e] * 128 + c * 8);
    }
    for (int idx = t; idx < EBK * 3; idx += 256) {
        int e = idx / 3, c = idx - e * 3;
        uint4 z; z.x = 0; z.y = 0; z.z = 0; z.w = 0;
        *(uint4*)&efb[e][264 + c * 8] = z;
    }
    __syncthreads();

    const int rb = w * 16;
    int rowr[4], slotr[4];
    float y0r[4];
#pragma unroll
    for (int reg = 0; reg < 4; ++reg) {
        rowr[reg] = rb + quad * 4 + reg;
        slotr[reg] = slot_l[rowr[reg]];
        y0r[reg] = y_l[rowr[reg]][0];
    }
    float wd1v[4];
#pragma unroll
    for (int q2 = 0; q2 < 4; ++q2) wd1v[q2] = Wd1[q2 * 16 + lr] * 0.125f;

    floatx4 c0[8];
#pragma unroll
    for (int nt = 0; nt < 8; ++nt) c0[nt] = (floatx4){0.f, 0.f, 0.f, 0.f};
    const unsigned short* arow = &efb[rb + lr][quad * 8];
#pragma unroll
    for (int kt = 0; kt < 9; ++kt) {
        short8 af = *(const short8*)(arow + kt * 32);
        const short8* bp = (const short8*)WB0 + (size_t)(kt * 8) * 64 + l;
#pragma unroll
        for (int nt = 0; nt < 8; ++nt) {
            short8 bf = bp[nt * 64];
            c0[nt] = __builtin_amdgcn_mfma_f32_16x16x32_bf16(af, bf, c0[nt], 0, 0, 0);
        }
    }
    float dp[4] = {0.f, 0.f, 0.f, 0.f};
#pragma unroll
    for (int nt = 0; nt < 4; ++nt) {
#pragma unroll
        for (int reg = 0; reg < 4; ++reg) {
            efb[rowr[reg]][nt * 16 + lr] = f2bf(silu_f(c0[nt][reg]));
            dp[reg] += silu_f(c0[nt + 4][reg]) * wd1v[nt];
        }
    }
#pragma unroll
    for (int m2 = 1; m2 < 16; m2 <<= 1) {
#pragma unroll
        for (int reg = 0; reg < 4; ++reg) dp[reg] += __shfl_xor(dp[reg], m2);
    }
    if (lr == 0) {
#pragma unroll
        for (int reg = 0; reg < 4; ++reg)
            metaP[(size_t)slotr[reg] * 8 + 4] = tanhf(dp[reg] * dp[reg]);
    }

    const unsigned short* hrow0 = &efb[rb + lr][quad * 8];
    const unsigned short* hrow1 = &efb[rb + lr][H1OFF + quad * 8];

    {
        floatx4 c1[4];
#pragma unroll
        for (int nt = 0; nt < 4; ++nt) c1[nt] = (floatx4){0.f, 0.f, 0.f, 0.f};
#pragma unroll
        for (int kt = 0; kt < 2; ++kt) {
            short8 af = *(const short8*)(hrow0 + kt * 32);
            const short8* bp = (const short8*)WB1 + (size_t)(kt * 4) * 64 + l;
#pragma unroll
            for (int nt = 0; nt < 4; ++nt)
                c1[nt] = __builtin_amdgcn_mfma_f32_16x16x32_bf16(af, bp[nt * 64], c1[nt], 0, 0, 0);
        }
#pragma unroll
        for (int nt = 0; nt < 4; ++nt)
#pragma unroll
            for (int reg = 0; reg < 4; ++reg)
                efb[rowr[reg]][H1OFF + nt * 16 + lr] = f2bf(silu_f(c1[nt][reg]));
    }

    {
        floatx4 c2[4];
#pragma unroll
        for (int nt = 0; nt < 4; ++nt) c2[nt] = (floatx4){0.f, 0.f, 0.f, 0.f};
#pragma unroll
        for (int kt = 0; kt < 2; ++kt) {
            short8 af = *(const short8*)(hrow1 + kt * 32);
            const short8* bp = (const short8*)WB2 + (size_t)(kt * 4) * 64 + l;
#pragma unroll
            for (int nt = 0; nt < 4; ++nt)
                c2[nt] = __builtin_amdgcn_mfma_f32_16x16x32_bf16(af, bp[nt * 64], c2[nt], 0, 0, 0);
        }
#pragma unroll
        for (int nt = 0; nt < 4; ++nt)
#pragma unroll
            for (int reg = 0; reg < 4; ++reg)
                efb[rowr[reg]][nt * 16 + lr] = f2bf(silu_f(c2[nt][reg]));
    }

    {
        short8 af0 = *(const short8*)(hrow0);
        short8 af1 = *(const short8*)(hrow0 + 32);
        uint2* tpw2 = (uint2*)tpwP;
#pragma unroll
        for (int j2 = 0; j2 < 8; ++j2) {
            floatx4 c3[4];
#pragma unroll
            for (int g = 0; g < 4; ++g) c3[g] = (floatx4){0.f, 0.f, 0.f, 0.f};
#pragma unroll
            for (int g = 0; g < 4; ++g) {
                const short8* b0 = (const short8*)WB3 + (size_t)(g * 8 + j2) * 64 + l;
                const short8* b1 = (const short8*)WB3 + (size_t)(32 + g * 8 + j2) * 64 + l;
                c3[g] = __builtin_amdgcn_mfma_f32_16x16x32_bf16(af0, *b0, c3[g], 0, 0, 0);
                c3[g] = __builtin_amdgcn_mfma_f32_16x16x32_bf16(af1, *b1, c3[g], 0, 0, 0);
            }
            const int u = j2 * 16 + lr;
#pragma unroll
            for (int reg = 0; reg < 4; ++reg) {
                float w1v = c3[0][reg] * y0r[reg];
                float w2v = c3[1][reg];
                float w3v = c3[2][reg] * y0r[reg];
                float w4v = c3[3][reg];
                uint2 p;
                p.x = (unsigned)f2bf(w1v) | ((unsigned)f2bf(w2v) << 16);
                p.y = (unsigned)f2bf(w3v) | ((unsigned)f2bf(w4v) << 16);
                tpw2[(size_t)slotr[reg] * 128 + u] = p;
            }
        }
    }
}

// ---------------------------------------------------------------------------
// Kernel C: per-node gather, unrolled x4 for memory-level parallelism.
// ---------------------------------------------------------------------------
__global__ __launch_bounds__(128) void node_gather(
    const unsigned short* __restrict__ tpwP, const float* __restrict__ metaP,
    const int* __restrict__ offs, const uint2* __restrict__ xq,
    const float* __restrict__ alpha_p, const float* __restrict__ beta_p,
    unsigned short* __restrict__ msgs_b, unsigned short* __restrict__ msgv_b)
{
    const int n = blockIdx.x;
    const int j = threadIdx.x;
    const int s0 = offs[n], s1 = offs[n + 1];
    const uint2* tpw2 = (const uint2*)tpwP;

    float as0 = 0.f, as1 = 0.f;
    float av0x = 0.f, av0y = 0.f, av0z = 0.f;
    float av1x = 0.f, av1y = 0.f, av1z = 0.f;
    float dsum = 0.f;

    int s = s0;
    for (; s + 4 <= s1; s += 4) {
        float4 ma[4]; float dn[4]; uint2 wv[4]; uint2 xv[4];
#pragma unroll
        for (int k = 0; k < 4; ++k) {
            ma[k] = *(const float4*)&metaP[(size_t)(s + k) * 8];
            dn[k] = metaP[(size_t)(s + k) * 8 + 4];
            wv[k] = tpw2[(size_t)(s + k) * 128 + j];
        }
#pragma unroll
        for (int k = 0; k < 4; ++k)
            xv[k] = xq[(size_t)__float_as_int(ma[k].x) * 128 + j];
#pragma unroll
        for (int k = 0; k < 4; ++k) {
            const float y1x = ma[k].y, y1y = ma[k].z, y1z = ma[k].w;
            dsum += dn[k];
            const float w1  = __uint_as_float(wv[k].x << 16);
            const float w2  = __uint_as_float(wv[k].x & 0xffff0000u);
            const float w3  = __uint_as_float(wv[k].y << 16);
            const float w4  = __uint_as_float(wv[k].y & 0xffff0000u);
            const float xs  = __uint_as_float(xv[k].x << 16);
            const float xvx = __uint_as_float(xv[k].x & 0xffff0000u);
            const float xvy = __uint_as_float(xv[k].y << 16);
            const float xvz = __uint_as_float(xv[k].y & 0xffff0000u);
            as0 += w1 * xs;
            as1 += w4 * (xvx * y1x + xvy * y1y + xvz * y1z);
            const float b2 = w2 * xs;
            av0x += b2 * y1x; av0y += b2 * y1y; av0z += b2 * y1z;
            av1x += w3 * xvx; av1y += w3 * xvy; av1z += w3 * xvz;
        }
    }
    for (; s < s1; ++s) {
        const float4 m0 = *(const float4*)&metaP[(size_t)s * 8];
        const float dns = metaP[(size_t)s * 8 + 4];
        const int snd = __float_as_int(m0.x);
        const float y1x = m0.y, y1y = m0.z, y1z = m0.w;
        dsum += dns;
        uint2 wv = tpw2[(size_t)s * 128 + j];
        uint2 xv = xq[(size_t)snd * 128 + j];
        const float w1  = __uint_as_float(wv.x << 16);
        const float w2  = __uint_as_float(wv.x & 0xffff0000u);
        const float w3  = __uint_as_float(wv.y << 16);
        const float w4  = __uint_as_float(wv.y & 0xffff0000u);
        const float xs  = __uint_as_float(xv.x << 16);
        const float xvx = __uint_as_float(xv.x & 0xffff0000u);
        const float xvy = __uint_as_float(xv.y << 16);
        const float xvz = __uint_as_float(xv.y & 0xffff0000u);
        as0 += w1 * xs;
        as1 += w4 * (xvx * y1x + xvy * y1y + xvz * y1z);
        const float b2 = w2 * xs;
        av0x += b2 * y1x; av0y += b2 * y1y; av0z += b2 * y1z;
        av1x += w3 * xvx; av1y += w3 * xvy; av1z += w3 * xvz;
    }

    const float invden = 1.f / (dsum * (*beta_p) + (*alpha_p));

    msgs_b[(size_t)n * 256 + j]       = f2bf(as0 * invden);
    msgs_b[(size_t)n * 256 + 128 + j] = f2bf(as1 * invden);
    msgv_b[((size_t)0 * NN + n) * 256 + j]       = f2bf(av0x * invden);
    msgv_b[((size_t)0 * NN + n) * 256 + 128 + j] = f2bf(av1x * invden);
    msgv_b[((size_t)1 * NN + n) * 256 + j]       = f2bf(av0y * invden);
    msgv_b[((size_t)1 * NN + n) * 256 + 128 + j] = f2bf(av1y * invden);
    msgv_b[((size_t)2 * NN + n) * 256 + j]       = f2bf(av0z * invden);
    msgv_b[((size_t)2 * NN + n) * 256 + 128 + j] = f2bf(av1z * invden);
}

// ---------------------------------------------------------------------------
// Kernel D1: scalar epilogue on MFMA (unchanged).
// ---------------------------------------------------------------------------
#define DNP 32
__global__ __launch_bounds__(256) void post_s(
    const unsigned short* __restrict__ msgs_b, const unsigned short* __restrict__ us_b,
    const unsigned short* __restrict__ WPs, const unsigned short* __restrict__ W2ss,
    float* __restrict__ gate, float* __restrict__ out)
{
    __shared__ __align__(16) unsigned short At[DNP][392];
    __shared__ __align__(16) unsigned short osb[DNP][136];
    const int t = threadIdx.x;
    const int l = t & 63, w = t >> 6;
    const int quad = l >> 4, lr = l & 15;
    const int n0 = blockIdx.x * DNP;
    const int rt = w & 1, nh = w >> 1;

    for (int idx = t; idx < DNP * 48; idx += 256) {
        int r = idx / 48, q = idx - r * 48;
        uint4 v;
        if (q < 32) v = *(const uint4*)(msgs_b + (size_t)(n0 + r) * 256 + q * 8);
        else        v = *(const uint4*)(us_b   + (size_t)(n0 + r) * 128 + (q - 32) * 8);
        *(uint4*)&At[r][q * 8] = v;
    }
    __syncthreads();

    int rowr[4];
#pragma unroll
    for (int reg = 0; reg < 4; ++reg) rowr[reg] = rt * 16 + quad * 4 + reg;

    floatx4 c1[8];
#pragma unroll
    for (int nt = 0; nt < 8; ++nt) c1[nt] = (floatx4){0.f, 0.f, 0.f, 0.f};
    const unsigned short* arow = &At[rt * 16 + lr][quad * 8];
#pragma unroll
    for (int kt = 0; kt < 12; ++kt) {
        short8 af = *(const short8*)(arow + kt * 32);
        const short8* bp = (const short8*)WPs + (size_t)(kt * 16 + nh * 8) * 64 + l;
#pragma unroll
        for (int nt = 0; nt < 8; ++nt)
            c1[nt] = __builtin_amdgcn_mfma_f32_16x16x32_bf16(af, bp[nt * 64], c1[nt], 0, 0, 0);
    }
    if (nh == 0) {
#pragma unroll
        for (int nt = 0; nt < 8; ++nt)
#pragma unroll
            for (int reg = 0; reg < 4; ++reg)
                osb[rowr[reg]][nt * 16 + lr] = f2bf(silu_f(c1[nt][reg]));
    } else {
#pragma unroll
        for (int nt = 0; nt < 8; ++nt)
#pragma unroll
            for (int reg = 0; reg < 4; ++reg)
                gate[(size_t)(n0 + rowr[reg]) * 128 + nt * 16 + lr] = sigm_f(c1[nt][reg]);
    }
    __syncthreads();

    floatx4 c2[4];
#pragma unroll
    for (int nt = 0; nt < 4; ++nt) c2[nt] = (floatx4){0.f, 0.f, 0.f, 0.f};
    const unsigned short* arow2 = &osb[rt * 16 + lr][quad * 8];
#pragma unroll
    for (int kt = 0; kt < 4; ++kt) {
        short8 af = *(const short8*)(arow2 + kt * 32);
        const short8* bp = (const short8*)W2ss + (size_t)(kt * 8 + nh * 4) * 64 + l;
#pragma unroll
        for (int nt = 0; nt < 4; ++nt)
            c2[nt] = __builtin_amdgcn_mfma_f32_16x16x32_bf16(af, bp[nt * 64], c2[nt], 0, 0, 0);
    }
#pragma unroll
    for (int nt = 0; nt < 4; ++nt)
#pragma unroll
        for (int reg = 0; reg < 4; ++reg)
            out[(size_t)(n0 + rowr[reg]) * 512 + (nh * 64 + nt * 16 + lr) * 4] = c2[nt][reg];
}

// ---------------------------------------------------------------------------
// Kernel D2: vector epilogue on MFMA (unchanged).
// ---------------------------------------------------------------------------
__global__ __launch_bounds__(256) void post_v(
    const unsigned short* __restrict__ msgv_b, const unsigned short* __restrict__ uv_b,
    const unsigned short* __restrict__ WPv, const unsigned short* __restrict__ W2vs,
    const float* __restrict__ gate, float* __restrict__ out)
{
    __shared__ __align__(16) unsigned short At[DNP][392];
    __shared__ __align__(16) unsigned short ovb[DNP][136];
    const int t = threadIdx.x;
    const int l = t & 63, w = t >> 6;
    const int quad = l >> 4, lr = l & 15;
    const int c = blockIdx.x >> 8;
    const int n0 = (blockIdx.x & 255) * DNP;
    const int rt = w & 1, nh = w >> 1;

    for (int idx = t; idx < DNP * 48; idx += 256) {
        int r = idx / 48, q = idx - r * 48;
        uint4 v;
        if (q < 32) v = *(const uint4*)(msgv_b + ((size_t)c * NN + n0 + r) * 256 + q * 8);
        else        v = *(const uint4*)(uv_b   + ((size_t)c * NN + n0 + r) * 128 + (q - 32) * 8);
        *(uint4*)&At[r][q * 8] = v;
    }
    __syncthreads();

    int rowr[4];
#pragma unroll
    for (int reg = 0; reg < 4; ++reg) rowr[reg] = rt * 16 + quad * 4 + reg;

    floatx4 c1[4];
#pragma unroll
    for (int nt = 0; nt < 4; ++nt) c1[nt] = (floatx4){0.f, 0.f, 0.f, 0.f};
    const unsigned short* arow = &At[rt * 16 + lr][quad * 8];
#pragma unroll
    for (int kt = 0; kt < 12; ++kt) {
        short8 af = *(const short8*)(arow + kt * 32);
        const short8* bp = (const short8*)WPv + (size_t)(kt * 8 + nh * 4) * 64 + l;
#pragma unroll
        for (int nt = 0; nt < 4; ++nt)
            c1[nt] = __builtin_amdgcn_mfma_f32_16x16x32_bf16(af, bp[nt * 64], c1[nt], 0, 0, 0);
    }
#pragma unroll
    for (int nt = 0; nt < 4; ++nt)
#pragma unroll
        for (int reg = 0; reg < 4; ++reg) {
            int col = nh * 64 + nt * 16 + lr;
            float g = gate[(size_t)(n0 + rowr[reg]) * 128 + col];
            ovb[rowr[reg]][col] = f2bf(c1[nt][reg] * g);
        }
    __syncthreads();

    floatx4 c2[4];
#pragma unroll
    for (int nt = 0; nt < 4; ++nt) c2[nt] = (floatx4){0.f, 0.f, 0.f, 0.f};
    const unsigned short* arow2 = &ovb[rt * 16 + lr][quad * 8];
#pragma unroll
    for (int kt = 0; kt < 4; ++kt) {
        short8 af = *(const short8*)(arow2 + kt * 32);
        const short8* bp = (const short8*)W2vs + (size_t)(kt * 8 + nh * 4) * 64 + l;
#pragma unroll
        for (int nt = 0; nt < 4; ++nt)
            c2[nt] = __builtin_amdgcn_mfma_f32_16x16x32_bf16(af, bp[nt * 64], c2[nt], 0, 0, 0);
    }
#pragma unroll
    for (int nt = 0; nt < 4; ++nt)
#pragma unroll
        for (int reg = 0; reg < 4; ++reg)
            out[(size_t)(n0 + rowr[reg]) * 512 + (nh * 64 + nt * 16 + lr) * 4 + 1 + c]
                = c2[nt][reg];
}

// ---------------------------------------------------------------------------
extern "C" void kernel_launch(void* const* d_in, const int* in_sizes, int n_in,
                              void* d_out, int out_size, void* d_ws, size_t ws_size,
                              hipStream_t stream)
{
    const float* node_attrs = (const float*)d_in[0];
    const float* node_feats = (const float*)d_in[1];
    const float* edge_attrs = (const float*)d_in[2];
    const float* edge_feats = (const float*)d_in[3];
    const int*   edge_index = (const int*)d_in[4];
    const float* W_skip_s = (const float*)d_in[5];
    const float* W_skip_v = (const float*)d_in[6];
    const float* W_up_s   = (const float*)d_in[7];
    const float* W_up_v   = (const float*)d_in[8];
    const float* W_src    = (const float*)d_in[9];
    const float* W_tgt    = (const float*)d_in[10];
    const float* W_r0     = (const float*)d_in[11];
    const float* W_r1     = (const float*)d_in[12];
    const float* W_r2     = (const float*)d_in[13];
    const float* W_r3     = (const float*)d_in[14];
    const float* W_d0     = (const float*)d_in[15];
    const float* W_d1     = (const float*)d_in[16];
    const float* W1_s     = (const float*)d_in[17];
    const float* W1_v     = (const float*)d_in[18];
    const float* Wres_s   = (const float*)d_in[19];
    const float* Wres_v   = (const float*)d_in[20];
    const float* W2_s     = (const float*)d_in[21];
    const float* W2_v     = (const float*)d_in[22];
    const float* alpha_p  = (const float*)d_in[23];
    const float* beta_p   = (const float*)d_in[24];

    float* out = (float*)d_out;
    float* sc_out = out + (size_t)NN * 512;
    float* ws = (float*)d_ws;

    uint2* xq = (uint2*)(ws + WS_XQ);
    unsigned short* us_b  = (unsigned short*)(ws + WS_USB);
    unsigned short* uv_b  = (unsigned short*)(ws + WS_UVB);
    unsigned short* srcEb = (unsigned short*)(ws + WS_SRC);
    unsigned short* tgtEb = (unsigned short*)(ws + WS_TGT);
    unsigned short* msgs_b = (unsigned short*)(ws + WS_MSGSB);
    unsigned short* msgv_b = (unsigned short*)(ws + WS_MSGVB);
    float* gate  = ws + WS_GATE;
    int*   counts = (int*)(ws + WS_COUNTS);
    int*   offs   = (int*)(ws + WS_OFFS);
    int*   cursor = (int*)(ws + WS_CURSOR);
    int*   pos    = (int*)(ws + WS_POS);
    float* metaP  = ws + WS_META;
    unsigned short* tpwP = (unsigned short*)(ws + WS_TPW);
    unsigned short* WBall = (unsigned short*)(ws + WS_WB);
    unsigned short* WB0 = WBall;
    unsigned short* WB1 = WB0 + (size_t)72 * 512;
    unsigned short* WB2 = WB1 + (size_t)8 * 512;
    unsigned short* WB3 = WB2 + (size_t)8 * 512;
    unsigned short* WPall = (unsigned short*)(ws + WS_WP);
    unsigned short* WPs  = WPall;
    unsigned short* WPv  = WPs + (size_t)192 * 512;
    unsigned short* W2ss = WPv + (size_t)96 * 512;
    unsigned short* W2vs = W2ss + (size_t)32 * 512;
    unsigned short* WN   = (unsigned short*)(ws + WS_WN);

    hipMemsetAsync(counts, 0, (size_t)NN * sizeof(int), stream);

    csr_count<<<EE / 256, 256, 0, stream>>>(edge_index, counts);
    csr_scan<<<1, 1024, 0, stream>>>(counts, offs, cursor);
    csr_scatter<<<EE / 256, 256, 0, stream>>>(edge_index, cursor, pos);

    swizzle_weights<<<38, 256, 0, stream>>>(W_r0, W_d0, W_r1, W_r2, W_r3, WBall);
    swizzle_post<<<88, 256, 0, stream>>>(W1_s, W1_v, Wres_s, Wres_v, W2_s, W2_v, WPall);
    swizzle_node<<<36, 256, 0, stream>>>(W_skip_s, W_up_s, W_skip_v, W_up_v,
                                         W_src, W_tgt, WN);

    node_pre_mfma<<<NN / PNB, 256, 0, stream>>>(
        node_attrs, node_feats, WN, sc_out, xq, us_b, uv_b, srcEb, tgtEb);

    edge_mlp<<<EE / EBK, 256, 0, stream>>>(
        edge_attrs, edge_feats, edge_index, srcEb, tgtEb,
        WB0, WB1, WB2, WB3, W_d1, pos, tpwP, metaP);

    node_gather<<<NN, 128, 0, stream>>>(
        tpwP, metaP, offs, xq, alpha_p, beta_p, msgs_b, msgv_b);

    post_s<<<NN / DNP, 256, 0, stream>>>(msgs_b, us_b, WPs, W2ss, gate, out);
    post_v<<<3 * NN / DNP, 256, 0, stream>>>(msgv_b, uv_b, WPv, W2vs, gate, out);
}